// Round 1
// 3107.196 us; speedup vs baseline: 2.1546x; 2.1546x over previous
//
#include <hip/hip_runtime.h>
#include <math.h>

// Problem constants
constexpr int kB   = 128;
constexpr int kP   = 196;     // 14*14
constexpr int kE   = 2048;
constexpr int kA   = 512;
constexpr int kEMB = 512;
constexpr int kD   = 512;
constexpr int kV   = 10000;
constexpr int kLC  = 128;
constexpr int kTCAP= 26;
constexpr int kT   = 25;
constexpr int kX   = kEMB + kLC + kE;   // 2688
constexpr int kXH  = kX + kD;           // 3200 = [x | h]
constexpr int kN3  = kV + kA + kE;      // 12560 = [W_fc | W_dec_att | W_fbeta] cols
constexpr int kBIG = 1 << 30;
constexpr int KZ   = 5;                 // split-K factor for gates GEMM (3200/5 = 640)

typedef __attribute__((ext_vector_type(8))) short bf8;
typedef __attribute__((ext_vector_type(4))) float f4;

__device__ inline float b2f(ushort u) { return __uint_as_float(((unsigned)u) << 16); }
__device__ inline ushort f2b(float f) {  // round-to-nearest-even
    unsigned u = __float_as_uint(f);
    return (ushort)((u + 0x7fffu + ((u >> 16) & 1u)) >> 16);
}

// ---------------------------------------------------------------------------
// Sort + gathers (single block, 128 threads). Stable descending argsort.
// ---------------------------------------------------------------------------
__global__ __launch_bounds__(128) void sort_setup(
    const int* __restrict__ caplen, const int* __restrict__ caps_in,
    const int* __restrict__ lclass, const float* __restrict__ lc_table,
    int* __restrict__ sort_ind, int* __restrict__ declen, int* __restrict__ caps_i,
    float* __restrict__ style,
    float* __restrict__ out_caps, float* __restrict__ out_declen,
    float* __restrict__ out_sortind)
{
    __shared__ int lens[kB];
    __shared__ int sind[kB];
    int i = threadIdx.x;
    lens[i] = caplen[i];
    __syncthreads();
    int li = lens[i];
    int r = 0;
    for (int j = 0; j < kB; j++) {
        int lj = lens[j];
        if (lj > li || (lj == li && j < i)) r++;
    }
    sind[r] = i;
    sort_ind[r] = i;
    out_sortind[r] = (float)i;
    __syncthreads();
    int orig = sind[i];
    int dl = lens[orig] - 1;
    declen[i] = dl;
    out_declen[i] = (float)dl;
    for (int t = 0; t < kTCAP; t++) {
        int cv = caps_in[orig * kTCAP + t];
        caps_i[i * kTCAP + t] = cv;
        out_caps[i * kTCAP + t] = (float)cv;
    }
    int lcl = lclass[orig];
    for (int k = 0; k < kLC; k++) style[i * kLC + k] = lc_table[lcl * kLC + k];
}

// ---------------------------------------------------------------------------
// Transpose-convert: dst[n][k] (bf16, row stride ldd) = src[k][n] (f32, ldsrc)
// Tiled 32x32 via LDS; conflict-free ([32][33] pad). Weights are static, so
// this runs once and makes GEMM B-staging fully vectorized (no b16 scatter).
// ---------------------------------------------------------------------------
__global__ __launch_bounds__(256) void tcvt_kernel(
    const float* __restrict__ src, int ldsrc, int K, int N,
    ushort* __restrict__ dst, long long ldd)
{
    __shared__ float tile[32][33];
    int k0 = blockIdx.y * 32, n0 = blockIdx.x * 32;
    int tx = threadIdx.x & 31, ty = threadIdx.x >> 5;   // 32 x 8
    #pragma unroll
    for (int j = 0; j < 4; j++) {
        int k = k0 + ty + j * 8, n = n0 + tx;
        tile[ty + j * 8][tx] = (k < K && n < N) ? src[(long long)k * ldsrc + n] : 0.f;
    }
    __syncthreads();
    #pragma unroll
    for (int j = 0; j < 4; j++) {
        int n = n0 + ty + j * 8, k = k0 + tx;
        if (n < N && k < K) dst[(long long)n * ldd + k] = f2b(tile[tx][ty + j * 8]);
    }
}

// bias3 = [b_fc | b_dec | b_fbeta]; bias_hc = [b_ih0 | b_ic0]; gbias = b_ih+b_hh
__global__ __launch_bounds__(256) void bias_setup_kernel(
    const float* __restrict__ b_fc, const float* __restrict__ b_dec,
    const float* __restrict__ b_fb, const float* __restrict__ b_ih0,
    const float* __restrict__ b_ic0, const float* __restrict__ b_ih,
    const float* __restrict__ b_hh,
    float* __restrict__ bias3, float* __restrict__ bias_hc, float* __restrict__ gbias)
{
    int idx = blockIdx.x * 256 + threadIdx.x;
    if (idx < kN3) {
        float v;
        if (idx < kV) v = b_fc[idx];
        else if (idx < kV + kA) v = b_dec[idx - kV];
        else v = b_fb[idx - kV - kA];
        bias3[idx] = v;
    } else if (idx < kN3 + 1024) {
        int i = idx - kN3;
        bias_hc[i] = (i < 512) ? b_ih0[i] : b_ic0[i - 512];
    } else if (idx < kN3 + 1024 + 2048) {
        int i = idx - kN3 - 1024;
        gbias[i] = b_ih[i] + b_hh[i];
    }
}

// enc (sorted) -> bf16: enc_bf[b][p][e] = bf16(enc[sort_ind[b]][p][e])
__global__ __launch_bounds__(256) void enc_cvt_kernel(
    const float* __restrict__ enc, const int* __restrict__ sort_ind,
    ushort* __restrict__ enc_bf)
{
    long long idx4 = (long long)blockIdx.x * 256 + threadIdx.x;
    if (idx4 >= (long long)kB * kP * kE / 4) return;
    int r = (int)(idx4 >> 9);          // dst row (b*196+p), 512 chunks/row
    int cc = ((int)idx4 & 511) * 4;
    int b = r / kP, p = r - b * kP;
    long long srow = (long long)sort_ind[b] * kP + p;
    float4 v = *(const float4*)(enc + srow * kE + cc);
    ushort4 o; o.x = f2b(v.x); o.y = f2b(v.y); o.z = f2b(v.z); o.w = f2b(v.w);
    *(ushort4*)(enc_bf + (long long)r * kE + cc) = o;
}

// mean over p (dual source: bf16 sorted, or f32 unsorted + sort_ind)
__global__ __launch_bounds__(256) void mean_enc_kernel(
    const float* __restrict__ encf, const ushort* __restrict__ encb, int use_bf,
    const int* __restrict__ sort_ind, float* __restrict__ me)
{
    int idx = blockIdx.x * 256 + threadIdx.x;   // b*2048 + e
    int b = idx >> 11, e = idx & 2047;
    float s = 0.f;
    if (use_bf) {
        const ushort* base = encb + (long long)b * kP * kE + e;
        #pragma unroll 4
        for (int p = 0; p < kP; p++) s += b2f(base[(long long)p * kE]);
    } else {
        const float* base = encf + (long long)sort_ind[b] * kP * kE + e;
        #pragma unroll 4
        for (int p = 0; p < kP; p++) s += base[(long long)p * kE];
    }
    me[idx] = s * (1.0f / 196.0f);
}

// ---------------------------------------------------------------------------
// bf16 MFMA GEMM v3: C = A[M,K] @ B[K,N] + bias, with B PRE-TRANSPOSED as
// Bt[N][K] (row stride ldbt). A is f32 (a_bf16=0) or bf16 (a_bf16=1).
// 64x128 tile, BK=32, 4 waves. Register-prefetch double buffering.
// Split-K via gridDim.z: block z computes K-slice [z*K/Z, (z+1)*K/Z) and
// writes out1 at offset z*zstride (partials reduced by consumer).
// Split epilogue: cols [0,split1) -> out1 (bf16 or f32, optional row mask),
// [split1,split2) -> out2 (f32), [split2,N) -> out3 (f32).
// M % 64 == 0, K % (32*gridDim.z) == 0 (all call sites).
// ---------------------------------------------------------------------------
__global__ __launch_bounds__(256) void gemm2(
    const void* __restrict__ Am, int lda, int a_bf16,
    const ushort* __restrict__ Bt, int ldbt,
    const float* __restrict__ bias,
    void* __restrict__ out1, long long ldc1, int c1_bf16,
    int split1, float* __restrict__ out2, long long ldc2,
    int split2, float* __restrict__ out3, long long ldc3,
    const int* __restrict__ declen, int t,
    int M, int N, int K, long long zstride)
{
    __shared__ short As[64][40];   // [m][k], +8 pad
    __shared__ short Bs[128][40];  // [n][k], +8 pad
    int tid = threadIdx.x;
    int lane = tid & 63, w = tid >> 6, quad = lane >> 4, l16 = lane & 15;
    int m0 = blockIdx.y * 64, n0 = blockIdx.x * 128;

    f4 acc[8];
    #pragma unroll
    for (int i = 0; i < 8; i++) acc[i] = (f4){0.f, 0.f, 0.f, 0.f};

    // A staging: thread -> (row a_r, 8 contiguous k at a_kc)
    int a_r = tid >> 2;
    int a_kc = (tid & 3) * 8;
    long long a_row = m0 + a_r;
    const float*  a_srcf = (const float*)Am  + a_row * (long long)lda + a_kc;
    const ushort* a_srcb = (const ushort*)Am + a_row * (long long)lda + a_kc;

    // B staging (transposed input): thread -> (row n = b_r, 16 contiguous k at b_kc)
    int b_r = tid >> 1;
    int b_kc = (tid & 1) * 16;
    bool bvalid = (n0 + b_r) < N;
    const ushort* b_src = Bt + (long long)(n0 + b_r) * ldbt + b_kc;

    int kpb = K / (int)gridDim.z;
    int kbeg = (int)blockIdx.z * kpb, kend = kbeg + kpb;

    float4 af0 = make_float4(0.f, 0.f, 0.f, 0.f), af1 = af0;
    uint4 au, bu0, bu1;
    au.x = au.y = au.z = au.w = 0u; bu0 = au; bu1 = au;

    // prologue prefetch
    if (a_bf16) au = *(const uint4*)(a_srcb + kbeg);
    else { af0 = *(const float4*)(a_srcf + kbeg); af1 = *(const float4*)(a_srcf + kbeg + 4); }
    if (bvalid) { bu0 = *(const uint4*)(b_src + kbeg); bu1 = *(const uint4*)(b_src + kbeg + 8); }

    for (int k0 = kbeg; k0 < kend; k0 += 32) {
        __syncthreads();                      // prior iteration's LDS reads done
        // --- store staged tile (all vectorized, 2-way-or-less read conflicts) ---
        if (a_bf16) {
            *(uint4*)&As[a_r][a_kc] = au;
        } else {
            uint4 pk; ushort* pp = (ushort*)&pk;
            pp[0] = f2b(af0.x); pp[1] = f2b(af0.y); pp[2] = f2b(af0.z); pp[3] = f2b(af0.w);
            pp[4] = f2b(af1.x); pp[5] = f2b(af1.y); pp[6] = f2b(af1.z); pp[7] = f2b(af1.w);
            *(uint4*)&As[a_r][a_kc] = pk;
        }
        *(uint4*)&Bs[b_r][b_kc]     = bu0;
        *(uint4*)&Bs[b_r][b_kc + 8] = bu1;
        // --- prefetch next tile into regs (overlaps barrier + MFMA phase) ---
        int kn = k0 + 32;
        if (kn < kend) {
            if (a_bf16) au = *(const uint4*)(a_srcb + kn);
            else { af0 = *(const float4*)(a_srcf + kn); af1 = *(const float4*)(a_srcf + kn + 4); }
            if (bvalid) { bu0 = *(const uint4*)(b_src + kn); bu1 = *(const uint4*)(b_src + kn + 8); }
        }
        __syncthreads();
        bf8 a = *(const bf8*)&As[w * 16 + l16][quad * 8];
        #pragma unroll
        for (int nt = 0; nt < 8; nt++) {
            bf8 b = *(const bf8*)&Bs[nt * 16 + l16][quad * 8];
            acc[nt] = __builtin_amdgcn_mfma_f32_16x16x32_bf16(a, b, acc[nt], 0, 0, 0);
        }
    }

    // Epilogue. C/D: col = lane&15, row = quad*4 + reg.
    long long zoff = (long long)blockIdx.z * zstride;
    #pragma unroll
    for (int nt = 0; nt < 8; nt++) {
        int cn = n0 + nt * 16 + l16;
        if (cn >= N) continue;
        float bv = bias ? bias[cn] : 0.f;
        #pragma unroll
        for (int reg = 0; reg < 4; reg++) {
            int rr = m0 + w * 16 + quad * 4 + reg;
            float v = acc[nt][reg] + bv;
            if (cn < split1) {
                if (declen && t >= declen[rr]) v = 0.f;
                long long idx = (long long)rr * ldc1 + cn + zoff;
                if (c1_bf16) ((ushort*)out1)[idx] = f2b(v);
                else         ((float*)out1)[idx] = v;
            } else if (cn < split2) {
                out2[(long long)rr * ldc2 + (cn - split1)] = v;
            } else {
                out3[(long long)rr * ldc3 + (cn - split2)] = v;
            }
        }
    }
}

// ---------------------------------------------------------------------------
// Attention energies + softmax. One block per batch row. att1 is bf16.
// Per-lane att2/w_full slices held in registers; 16B att1 loads.
// ---------------------------------------------------------------------------
__global__ __launch_bounds__(256) void attn_softmax_kernel(
    const ushort* __restrict__ att1, const float* __restrict__ att2,
    const float* __restrict__ w_full, const float* __restrict__ b_full,
    float* __restrict__ alpha, float* __restrict__ alphas_out,
    const int* __restrict__ declen, int t)
{
    int b = blockIdx.x;
    __shared__ float es[kP];
    __shared__ float red1[4], red2[4];
    int tid = threadIdx.x;
    int wave = tid >> 6, lane = tid & 63;
    float a2r[8], wfr[8];
    {
        const float4* ap = (const float4*)(att2 + (long long)b * kA + lane * 8);
        *(float4*)&a2r[0] = ap[0]; *(float4*)&a2r[4] = ap[1];
        const float4* wp = (const float4*)(w_full + lane * 8);
        *(float4*)&wfr[0] = wp[0]; *(float4*)&wfr[4] = wp[1];
    }
    float bf = b_full[0];
    const ushort* a1base = att1 + (long long)b * kP * kA + lane * 8;
    #pragma unroll 2
    for (int p0 = 0; p0 < kP; p0 += 4) {         // 196 = 4 waves * 49, exact
        int p = p0 + wave;
        uint4 u = *(const uint4*)(a1base + (long long)p * kA);
        const unsigned* uw = (const unsigned*)&u;
        float s = 0.f;
        #pragma unroll
        for (int j = 0; j < 4; j++) {
            unsigned x = uw[j];
            float v0 = b2f((ushort)(x & 0xffffu)) + a2r[2 * j];
            float v1 = b2f((ushort)(x >> 16))     + a2r[2 * j + 1];
            s += fmaxf(v0, 0.f) * wfr[2 * j] + fmaxf(v1, 0.f) * wfr[2 * j + 1];
        }
        #pragma unroll
        for (int off = 32; off; off >>= 1) s += __shfl_down(s, off);
        if (lane == 0) es[p] = s + bf;
    }
    __syncthreads();
    float e = (tid < kP) ? es[tid] : -1e30f;
    float wm = e;
    for (int off = 32; off; off >>= 1) wm = fmaxf(wm, __shfl_down(wm, off));
    if (lane == 0) red1[wave] = wm;
    __syncthreads();
    float gm = fmaxf(fmaxf(red1[0], red1[1]), fmaxf(red1[2], red1[3]));
    float ex = (tid < kP) ? expf(e - gm) : 0.f;
    float sw = ex;
    for (int off = 32; off; off >>= 1) sw += __shfl_down(sw, off);
    if (lane == 0) red2[wave] = sw;
    __syncthreads();
    float S = red2[0] + red2[1] + red2[2] + red2[3];
    if (tid < kP) {
        float a = ex / S;
        alpha[b * kP + tid] = a;
        alphas_out[((long long)b * kT + t) * kP + tid] = (t < declen[b]) ? a : 0.f;
    }
}

// ---------------------------------------------------------------------------
// Fused awe + build_x, vectorized. grid (3, kB):
//   blockIdx.x in {0,1}: awe cols, 4 per thread (ushort4/float4 loads)
//   blockIdx.x == 2:     emb + style cols [0,640)
// ---------------------------------------------------------------------------
__global__ __launch_bounds__(256) void awe_buildx_kernel(
    const float* __restrict__ encf, const ushort* __restrict__ encb, int use_bf,
    const int* __restrict__ sort_ind, const float* __restrict__ alpha,
    const float* __restrict__ gate, const int* __restrict__ caps_i, int t,
    const float* __restrict__ emb_table, const float* __restrict__ style,
    float* __restrict__ xh)
{
    int b = blockIdx.y;
    if (blockIdx.x == 2) {
        int tx = threadIdx.x;
        if (tx < kEMB / 4) {
            int tok = caps_i[b * kTCAP + t];
            float4 v = *(const float4*)(emb_table + (long long)tok * kEMB + tx * 4);
            *(float4*)(xh + (long long)b * kXH + tx * 4) = v;
        } else if (tx < kEMB / 4 + kLC / 4) {
            int j = tx - kEMB / 4;
            float4 v = *(const float4*)(style + b * kLC + j * 4);
            *(float4*)(xh + (long long)b * kXH + kEMB + j * 4) = v;
        }
        return;
    }
    __shared__ float al[kP];
    int tid = threadIdx.x;
    if (tid < kP) al[tid] = alpha[b * kP + tid];
    __syncthreads();
    int c0 = (blockIdx.x * 256 + tid) * 4;       // e2 base in [0, 2048)
    float a0 = 0.f, a1 = 0.f, a2 = 0.f, a3 = 0.f;
    if (use_bf) {
        const ushort* base = encb + (long long)b * kP * kE + c0;
        #pragma unroll 4
        for (int p = 0; p < kP; p++) {
            uint2 u = *(const uint2*)(base + (long long)p * kE);
            float ap = al[p];
            a0 += b2f((ushort)(u.x & 0xffffu)) * ap;
            a1 += b2f((ushort)(u.x >> 16))     * ap;
            a2 += b2f((ushort)(u.y & 0xffffu)) * ap;
            a3 += b2f((ushort)(u.y >> 16))     * ap;
        }
    } else {
        const float* base = encf + (long long)sort_ind[b] * kP * kE + c0;
        #pragma unroll 4
        for (int p = 0; p < kP; p++) {
            float4 v = *(const float4*)(base + (long long)p * kE);
            float ap = al[p];
            a0 += v.x * ap; a1 += v.y * ap; a2 += v.z * ap; a3 += v.w * ap;
        }
    }
    float4 g = *(const float4*)(gate + (long long)b * kE + c0);
    float4 o;
    o.x = a0 / (1.f + expf(-g.x));
    o.y = a1 / (1.f + expf(-g.y));
    o.z = a2 / (1.f + expf(-g.z));
    o.w = a3 / (1.f + expf(-g.w));
    *(float4*)(xh + (long long)b * kXH + kEMB + kLC + c0) = o;
}

// ---------------------------------------------------------------------------
// LSTM cell; reduces KZ split-K partials + gbias. h lives in xh[:, 2688:3200].
// ---------------------------------------------------------------------------
__global__ __launch_bounds__(256) void lstm_cell_kernel(
    const float* __restrict__ gpart, const float* __restrict__ gbias,
    float* __restrict__ xh, float* __restrict__ c)
{
    int idx = blockIdx.x * 256 + threadIdx.x;   // b*512 + d
    int b = idx >> 9, d = idx & 511;
    float gi = gbias[d], gf = gbias[kD + d], gg = gbias[2 * kD + d], go = gbias[3 * kD + d];
    const float* g = gpart + (long long)b * 4 * kD + d;
    #pragma unroll
    for (int z = 0; z < KZ; z++) {
        const float* gz = g + (long long)z * kB * 4 * kD;
        gi += gz[0]; gf += gz[kD]; gg += gz[2 * kD]; go += gz[3 * kD];
    }
    float si = 1.f / (1.f + expf(-gi));
    float sf = 1.f / (1.f + expf(-gf));
    float so = 1.f / (1.f + expf(-go));
    float cn = sf * c[idx] + si * tanhf(gg);
    float hn = so * tanhf(cn);
    c[idx] = cn;
    xh[(long long)b * kXH + kX + d] = hn;
}

// ---------------------------------------------------------------------------
extern "C" void kernel_launch(void* const* d_in, const int* in_sizes, int n_in,
                              void* d_out, int out_size, void* d_ws, size_t ws_size,
                              hipStream_t stream)
{
    const float* encoder_out  = (const float*)d_in[0];
    const int*   enc_caps     = (const int*)  d_in[1];
    const int*   cap_lengths  = (const int*)  d_in[2];
    const int*   length_class = (const int*)  d_in[3];
    const float* W_enc_att = (const float*)d_in[4];
    const float* b_enc_att = (const float*)d_in[5];
    const float* W_dec_att = (const float*)d_in[6];
    const float* b_dec_att = (const float*)d_in[7];
    const float* w_full_att = (const float*)d_in[8];
    const float* b_full_att = (const float*)d_in[9];
    const float* W_init_h = (const float*)d_in[10];
    const float* b_init_h = (const float*)d_in[11];
    const float* W_init_c = (const float*)d_in[12];
    const float* b_init_c = (const float*)d_in[13];
    const float* W_fbeta  = (const float*)d_in[14];
    const float* b_fbeta  = (const float*)d_in[15];
    const float* emb_table = (const float*)d_in[16];
    const float* lc_table  = (const float*)d_in[17];
    const float* W_fc = (const float*)d_in[18];
    const float* b_fc = (const float*)d_in[19];
    const float* W_ih = (const float*)d_in[20];
    const float* b_ih = (const float*)d_in[21];
    const float* W_hh = (const float*)d_in[22];
    const float* b_hh = (const float*)d_in[23];

    // Output layout (flat float32, reference return order)
    float* out = (float*)d_out;
    float* o_pred    = out;                                  // B*T*V
    float* o_caps    = out + (long long)kB * kT * kV;
    float* o_declen  = o_caps + kB * kTCAP;
    float* o_alpha   = o_declen + kB;
    float* o_sortind = o_alpha + (long long)kB * kT * kP;

    // Workspace carve: f32 region, bf16 region, int region.
    float* w = (float*)d_ws;
    float* xh       = w; w += kB * kXH;
    float* c        = w; w += kB * kD;
    float* att2     = w; w += kB * kA;
    float* gate     = w; w += kB * kE;
    float* mean_enc = w; w += kB * kE;
    float* gpart    = w; w += (long long)kB * 4 * kD * KZ;  // split-K partials
    float* alpha    = w; w += kB * kP;
    float* style    = w; w += kB * kLC;
    float* bias3    = w; w += kN3;
    float* bias_hc  = w; w += 1024;
    float* gbias    = w; w += 2048;
    ushort* us = (ushort*)w;
    ushort* att1_bf  = us; us += (long long)kB * kP * kA;   // 12.85M
    ushort* WencT    = us; us += (long long)kA * kE;        // [512][2048]
    ushort* WhcT     = us; us += (long long)1024 * kE;      // [1024][2048]
    ushort* WcatT    = us; us += (long long)(4 * kD) * kXH; // [2048][3200]
    ushort* Wcat3T   = us; us += (long long)kN3 * kD;       // [12560][512]
    int* iw = (int*)us;
    int* sort_ind = iw; iw += kB;
    int* declen   = iw; iw += kB;
    int* caps_i   = iw; iw += kB * kTCAP;
    ushort* enc_bf = (ushort*)(iw + kB);  // optional, 102.8 MB

    // Decide enc-bf16 path by workspace headroom (ws_size is call-invariant).
    size_t need_with_enc = ((char*)(enc_bf + (long long)kB * kP * kE)) - (char*)d_ws;
    int use_encbf = (ws_size >= need_with_enc) ? 1 : 0;

    sort_setup<<<1, 128, 0, stream>>>(cap_lengths, enc_caps, length_class, lc_table,
        sort_ind, declen, caps_i, style, o_caps, o_declen, o_sortind);

    // One-time weight prep: transpose-convert all B matrices to [N][K] bf16.
    auto tc = [&](const float* s, int ldsrc, int Kr, int Nc, ushort* d, long long ldd) {
        tcvt_kernel<<<dim3((Nc + 31) / 32, (Kr + 31) / 32), 256, 0, stream>>>(
            s, ldsrc, Kr, Nc, d, ldd);
    };
    tc(W_enc_att, kA, kE, kA, WencT, kE);                       // [512][2048]
    tc(W_init_h,  kD, kE, kD, WhcT, kE);                        // rows 0..512
    tc(W_init_c,  kD, kE, kD, WhcT + (long long)kD * kE, kE);   // rows 512..1024
    tc(W_ih, 4 * kD, kX, 4 * kD, WcatT, kXH);                   // k in [0,2688)
    tc(W_hh, 4 * kD, kD, 4 * kD, WcatT + kX, kXH);              // k in [2688,3200)
    tc(W_fc,      kV, kD, kV, Wcat3T, kD);                      // rows 0..10000
    tc(W_dec_att, kA, kD, kA, Wcat3T + (long long)kV * kD, kD); // rows 10000..10512
    tc(W_fbeta,   kE, kD, kE, Wcat3T + (long long)(kV + kA) * kD, kD);
    bias_setup_kernel<<<(kN3 + 1024 + 2048 + 255) / 256, 256, 0, stream>>>(
        b_fc, b_dec_att, b_fbeta, b_init_h, b_init_c, b_ih, b_hh, bias3, bias_hc, gbias);

    if (use_encbf) {
        enc_cvt_kernel<<<(unsigned)(((long long)kB * kP * kE / 4 + 255) / 256), 256, 0, stream>>>(
            encoder_out, sort_ind, enc_bf);
    }
    mean_enc_kernel<<<(kB * kE) / 256, 256, 0, stream>>>(
        encoder_out, enc_bf, use_encbf, sort_ind, mean_enc);

    auto g2 = [](int M, int N) { return dim3((unsigned)((N + 127) / 128), (unsigned)(M / 64)); };

    // h0 | c0 in one GEMM (split epilogue)
    gemm2<<<g2(kB, 1024), 256, 0, stream>>>(mean_enc, kE, 0, WhcT, kE, bias_hc,
        xh + kX, kXH, 0, 512, c, kD, kBIG, nullptr, 0, nullptr, 0, kB, 1024, kE, 0);

    // att1 (bf16) = enc_sorted @ W_enc_att + b_enc_att
    if (use_encbf) {
        gemm2<<<g2(kB * kP, kA), 256, 0, stream>>>(enc_bf, kE, 1, WencT, kE, b_enc_att,
            att1_bf, kA, 1, kBIG, nullptr, 0, kBIG, nullptr, 0, nullptr, 0,
            kB * kP, kA, kE, 0);
    } else {
        gemm2<<<g2(kB * kP, kA), 256, 0, stream>>>(encoder_out, kE, 0, WencT, kE, b_enc_att,
            att1_bf, kA, 1, kBIG, nullptr, 0, kBIG, nullptr, 0, nullptr, 0,
            kB * kP, kA, kE, 0);
    }

    // pre-loop: att2/gate for t=0 from h0
    gemm2<<<g2(kB, kA + kE), 256, 0, stream>>>(xh + kX, kXH, 0,
        Wcat3T + (long long)kV * kD, kD, bias3 + kV, att2, kA, 0,
        kA, gate, kE, kBIG, nullptr, 0, nullptr, 0, kB, kA + kE, kD, 0);

    for (int t = 0; t < kT; t++) {
        attn_softmax_kernel<<<kB, 256, 0, stream>>>(att1_bf, att2, w_full_att,
            b_full_att, alpha, o_alpha, declen, t);
        awe_buildx_kernel<<<dim3(3, kB), 256, 0, stream>>>(
            encoder_out, enc_bf, use_encbf, sort_ind, alpha, gate, caps_i, t,
            emb_table, style, xh);
        // gates partials via split-K (KZ slices of K=3200)
        gemm2<<<dim3((4 * kD + 127) / 128, kB / 64, KZ), 256, 0, stream>>>(
            xh, kXH, 0, WcatT, kXH, nullptr,
            gpart, 4 * kD, 0, kBIG, nullptr, 0, kBIG, nullptr, 0, nullptr, 0,
            kB, 4 * kD, kXH, (long long)kB * 4 * kD);
        lstm_cell_kernel<<<(kB * kD) / 256, 256, 0, stream>>>(gpart, gbias, xh, c);
        // fused: preds_t | att2_{t+1} | gate_{t+1}
        gemm2<<<g2(kB, kN3), 256, 0, stream>>>(xh + kX, kXH, 0, Wcat3T, kD, bias3,
            o_pred + (long long)t * kV, (long long)kT * kV, 0,
            kV, att2, kA, kV + kA, gate, kE, declen, t, kB, kN3, kD, 0);
    }
}

// Round 2
// 2833.030 us; speedup vs baseline: 2.3631x; 1.0968x over previous
//
#include <hip/hip_runtime.h>
#include <math.h>

// Problem constants
constexpr int kB   = 128;
constexpr int kP   = 196;     // 14*14
constexpr int kE   = 2048;
constexpr int kA   = 512;
constexpr int kEMB = 512;
constexpr int kD   = 512;
constexpr int kV   = 10000;
constexpr int kLC  = 128;
constexpr int kTCAP= 26;
constexpr int kT   = 25;
constexpr int kX   = kEMB + kLC + kE;   // 2688
constexpr int kXH  = kX + kD;           // 3200 = [x | h]
constexpr int kN3  = kV + kA + kE;      // 12560 = [W_fc | W_dec_att | W_fbeta] cols
constexpr int kBIG = 1 << 30;
constexpr int KZ   = 5;                 // split-K factor for gates GEMM (3200/5 = 640)

typedef __attribute__((ext_vector_type(8))) short bf8;
typedef __attribute__((ext_vector_type(4))) float f4;

__device__ inline float b2f(ushort u) { return __uint_as_float(((unsigned)u) << 16); }
__device__ inline ushort f2b(float f) {  // round-to-nearest-even
    unsigned u = __float_as_uint(f);
    return (ushort)((u + 0x7fffu + ((u >> 16) & 1u)) >> 16);
}

// XOR-swizzled LDS short-index for GEMM tiles: logical (row r, col k shorts),
// row stride 32 shorts (64B). XOR of ((r&7)<<3) spreads the 4 16B-groups of
// each row across the 8 16B bank-slots of a 128B superblock -> b128 reads are
// exact 2-way (free), b128 writes perfectly uniform. Bijective (bit 5 crosses
// into the row-pair bit but the map stays injective).
#define SWZ(r, k) ((((r) * 32) + (k)) ^ (((r) & 7) << 3))

// ---------------------------------------------------------------------------
// Sort + gathers (single block, 128 threads). Stable descending argsort.
// ---------------------------------------------------------------------------
__global__ __launch_bounds__(128) void sort_setup(
    const int* __restrict__ caplen, const int* __restrict__ caps_in,
    const int* __restrict__ lclass, const float* __restrict__ lc_table,
    int* __restrict__ sort_ind, int* __restrict__ declen, int* __restrict__ caps_i,
    float* __restrict__ style,
    float* __restrict__ out_caps, float* __restrict__ out_declen,
    float* __restrict__ out_sortind)
{
    __shared__ int lens[kB];
    __shared__ int sind[kB];
    int i = threadIdx.x;
    lens[i] = caplen[i];
    __syncthreads();
    int li = lens[i];
    int r = 0;
    for (int j = 0; j < kB; j++) {
        int lj = lens[j];
        if (lj > li || (lj == li && j < i)) r++;
    }
    sind[r] = i;
    sort_ind[r] = i;
    out_sortind[r] = (float)i;
    __syncthreads();
    int orig = sind[i];
    int dl = lens[orig] - 1;
    declen[i] = dl;
    out_declen[i] = (float)dl;
    for (int t = 0; t < kTCAP; t++) {
        int cv = caps_in[orig * kTCAP + t];
        caps_i[i * kTCAP + t] = cv;
        out_caps[i * kTCAP + t] = (float)cv;
    }
    int lcl = lclass[orig];
    for (int k = 0; k < kLC; k++) style[i * kLC + k] = lc_table[lcl * kLC + k];
}

// ---------------------------------------------------------------------------
// Transpose-convert: dst[n][k] (bf16, row stride ldd) = src[k][n] (f32, ldsrc)
// ---------------------------------------------------------------------------
__global__ __launch_bounds__(256) void tcvt_kernel(
    const float* __restrict__ src, int ldsrc, int K, int N,
    ushort* __restrict__ dst, long long ldd)
{
    __shared__ float tile[32][33];
    int k0 = blockIdx.y * 32, n0 = blockIdx.x * 32;
    int tx = threadIdx.x & 31, ty = threadIdx.x >> 5;   // 32 x 8
    #pragma unroll
    for (int j = 0; j < 4; j++) {
        int k = k0 + ty + j * 8, n = n0 + tx;
        tile[ty + j * 8][tx] = (k < K && n < N) ? src[(long long)k * ldsrc + n] : 0.f;
    }
    __syncthreads();
    #pragma unroll
    for (int j = 0; j < 4; j++) {
        int n = n0 + ty + j * 8, k = k0 + tx;
        if (n < N && k < K) dst[(long long)n * ldd + k] = f2b(tile[tx][ty + j * 8]);
    }
}

// bias3 = [b_fc | b_dec | b_fbeta]; bias_hc = [b_ih0 | b_ic0]; gbias = b_ih+b_hh
__global__ __launch_bounds__(256) void bias_setup_kernel(
    const float* __restrict__ b_fc, const float* __restrict__ b_dec,
    const float* __restrict__ b_fb, const float* __restrict__ b_ih0,
    const float* __restrict__ b_ic0, const float* __restrict__ b_ih,
    const float* __restrict__ b_hh,
    float* __restrict__ bias3, float* __restrict__ bias_hc, float* __restrict__ gbias)
{
    int idx = blockIdx.x * 256 + threadIdx.x;
    if (idx < kN3) {
        float v;
        if (idx < kV) v = b_fc[idx];
        else if (idx < kV + kA) v = b_dec[idx - kV];
        else v = b_fb[idx - kV - kA];
        bias3[idx] = v;
    } else if (idx < kN3 + 1024) {
        int i = idx - kN3;
        bias_hc[i] = (i < 512) ? b_ih0[i] : b_ic0[i - 512];
    } else if (idx < kN3 + 1024 + 2048) {
        int i = idx - kN3 - 1024;
        gbias[i] = b_ih[i] + b_hh[i];
    }
}

// enc (sorted) -> bf16: enc_bf[b][p][e] = bf16(enc[sort_ind[b]][p][e])
__global__ __launch_bounds__(256) void enc_cvt_kernel(
    const float* __restrict__ enc, const int* __restrict__ sort_ind,
    ushort* __restrict__ enc_bf)
{
    long long idx4 = (long long)blockIdx.x * 256 + threadIdx.x;
    if (idx4 >= (long long)kB * kP * kE / 4) return;
    int r = (int)(idx4 >> 9);          // dst row (b*196+p), 512 chunks/row
    int cc = ((int)idx4 & 511) * 4;
    int b = r / kP, p = r - b * kP;
    long long srow = (long long)sort_ind[b] * kP + p;
    float4 v = *(const float4*)(enc + srow * kE + cc);
    ushort4 o; o.x = f2b(v.x); o.y = f2b(v.y); o.z = f2b(v.z); o.w = f2b(v.w);
    *(ushort4*)(enc_bf + (long long)r * kE + cc) = o;
}

// mean over p (dual source: bf16 sorted, or f32 unsorted + sort_ind)
__global__ __launch_bounds__(256) void mean_enc_kernel(
    const float* __restrict__ encf, const ushort* __restrict__ encb, int use_bf,
    const int* __restrict__ sort_ind, float* __restrict__ me)
{
    int idx = blockIdx.x * 256 + threadIdx.x;   // b*2048 + e
    int b = idx >> 11, e = idx & 2047;
    float s = 0.f;
    if (use_bf) {
        const ushort* base = encb + (long long)b * kP * kE + e;
        #pragma unroll 4
        for (int p = 0; p < kP; p++) s += b2f(base[(long long)p * kE]);
    } else {
        const float* base = encf + (long long)sort_ind[b] * kP * kE + e;
        #pragma unroll 4
        for (int p = 0; p < kP; p++) s += base[(long long)p * kE];
    }
    me[idx] = s * (1.0f / 196.0f);
}

// ---------------------------------------------------------------------------
// bf16 MFMA GEMM v4: C = A[M,K] @ B[K,N] + bias, B pre-transposed Bt[N][K].
// A f32 (a_bf16=0) or bf16 (a_bf16=1). 64x128 tile, BK=32, 4 waves.
// XOR-swizzled LDS (conflict-free), register-prefetch double buffering.
// Split-K via gridDim.z (partials at z*zstride). Split epilogue as before.
// pred_mode: out1 rows are r = t*128 + b; write ((b*kT + t)*ldc1 + cn),
// masked by t >= declen[b].
// ---------------------------------------------------------------------------
__global__ __launch_bounds__(256) void gemm2(
    const void* __restrict__ Am, int lda, int a_bf16,
    const ushort* __restrict__ Bt, int ldbt,
    const float* __restrict__ bias,
    void* __restrict__ out1, long long ldc1, int c1_bf16,
    int split1, float* __restrict__ out2, long long ldc2,
    int split2, float* __restrict__ out3, long long ldc3,
    const int* __restrict__ declen, int t, int pred_mode,
    int M, int N, int K, long long zstride)
{
    __shared__ short As[64 * 32];    // swizzled, 64B row stride
    __shared__ short Bs[128 * 32];
    int tid = threadIdx.x;
    int lane = tid & 63, w = tid >> 6, quad = lane >> 4, l16 = lane & 15;
    int m0 = blockIdx.y * 64, n0 = blockIdx.x * 128;

    f4 acc[8];
    #pragma unroll
    for (int i = 0; i < 8; i++) acc[i] = (f4){0.f, 0.f, 0.f, 0.f};

    // A staging: thread -> (row a_r, 8 contiguous k at a_kc)
    int a_r = tid >> 2;
    int a_kc = (tid & 3) * 8;
    long long a_row = m0 + a_r;
    const float*  a_srcf = (const float*)Am  + a_row * (long long)lda + a_kc;
    const ushort* a_srcb = (const ushort*)Am + a_row * (long long)lda + a_kc;

    // B staging (transposed input): thread -> (row n = b_r, 16 contiguous k at b_kc)
    int b_r = tid >> 1;
    int b_kc = (tid & 1) * 16;
    bool bvalid = (n0 + b_r) < N;
    const ushort* b_src = Bt + (long long)(n0 + b_r) * ldbt + b_kc;

    int kpb = K / (int)gridDim.z;
    int kbeg = (int)blockIdx.z * kpb, kend = kbeg + kpb;

    float4 af0 = make_float4(0.f, 0.f, 0.f, 0.f), af1 = af0;
    uint4 au, bu0, bu1;
    au.x = au.y = au.z = au.w = 0u; bu0 = au; bu1 = au;

    // prologue prefetch
    if (a_bf16) au = *(const uint4*)(a_srcb + kbeg);
    else { af0 = *(const float4*)(a_srcf + kbeg); af1 = *(const float4*)(a_srcf + kbeg + 4); }
    if (bvalid) { bu0 = *(const uint4*)(b_src + kbeg); bu1 = *(const uint4*)(b_src + kbeg + 8); }

    for (int k0 = kbeg; k0 < kend; k0 += 32) {
        __syncthreads();                      // prior iteration's LDS reads done
        if (a_bf16) {
            *(uint4*)&As[SWZ(a_r, a_kc)] = au;
        } else {
            uint4 pk; ushort* pp = (ushort*)&pk;
            pp[0] = f2b(af0.x); pp[1] = f2b(af0.y); pp[2] = f2b(af0.z); pp[3] = f2b(af0.w);
            pp[4] = f2b(af1.x); pp[5] = f2b(af1.y); pp[6] = f2b(af1.z); pp[7] = f2b(af1.w);
            *(uint4*)&As[SWZ(a_r, a_kc)] = pk;
        }
        *(uint4*)&Bs[SWZ(b_r, b_kc)]     = bu0;
        *(uint4*)&Bs[SWZ(b_r, b_kc + 8)] = bu1;
        // prefetch next tile into regs (overlaps barrier + MFMA phase)
        int kn = k0 + 32;
        if (kn < kend) {
            if (a_bf16) au = *(const uint4*)(a_srcb + kn);
            else { af0 = *(const float4*)(a_srcf + kn); af1 = *(const float4*)(a_srcf + kn + 4); }
            if (bvalid) { bu0 = *(const uint4*)(b_src + kn); bu1 = *(const uint4*)(b_src + kn + 8); }
        }
        __syncthreads();
        bf8 a = *(const bf8*)&As[SWZ(w * 16 + l16, quad * 8)];
        #pragma unroll
        for (int nt = 0; nt < 8; nt++) {
            bf8 b = *(const bf8*)&Bs[SWZ(nt * 16 + l16, quad * 8)];
            acc[nt] = __builtin_amdgcn_mfma_f32_16x16x32_bf16(a, b, acc[nt], 0, 0, 0);
        }
    }

    // Epilogue. C/D: col = lane&15, row = quad*4 + reg.
    long long zoff = (long long)blockIdx.z * zstride;
    #pragma unroll
    for (int nt = 0; nt < 8; nt++) {
        int cn = n0 + nt * 16 + l16;
        if (cn >= N) continue;
        float bv = bias ? bias[cn] : 0.f;
        #pragma unroll
        for (int reg = 0; reg < 4; reg++) {
            int rr = m0 + w * 16 + quad * 4 + reg;
            float v = acc[nt][reg] + bv;
            if (cn < split1) {
                long long idx;
                if (pred_mode) {
                    int bb = rr & 127, tt = rr >> 7;
                    if (tt >= declen[bb]) v = 0.f;
                    idx = ((long long)bb * kT + tt) * ldc1 + cn;
                } else {
                    if (declen && t >= declen[rr]) v = 0.f;
                    idx = (long long)rr * ldc1 + cn + zoff;
                }
                if (c1_bf16) ((ushort*)out1)[idx] = f2b(v);
                else         ((float*)out1)[idx] = v;
            } else if (cn < split2) {
                out2[(long long)rr * ldc2 + (cn - split1)] = v;
            } else {
                out3[(long long)rr * ldc3 + (cn - split2)] = v;
            }
        }
    }
}

// ---------------------------------------------------------------------------
// Attention energies + softmax. One block (512 thr) per batch row.
// smap: optional row gather for att1 (nullptr = identity).
// ---------------------------------------------------------------------------
__global__ __launch_bounds__(512) void attn_softmax_kernel(
    const ushort* __restrict__ att1, const float* __restrict__ att2,
    const float* __restrict__ w_full, const float* __restrict__ b_full,
    float* __restrict__ alpha, float* __restrict__ alphas_out,
    const int* __restrict__ declen, int t, const int* __restrict__ smap)
{
    int b = blockIdx.x;
    int ob = smap ? smap[b] : b;
    __shared__ float es[kP];
    __shared__ float red1[8], red2[8];
    int tid = threadIdx.x;
    int wave = tid >> 6, lane = tid & 63;
    float a2r[8], wfr[8];
    {
        const float4* ap = (const float4*)(att2 + (long long)b * kA + lane * 8);
        *(float4*)&a2r[0] = ap[0]; *(float4*)&a2r[4] = ap[1];
        const float4* wp = (const float4*)(w_full + lane * 8);
        *(float4*)&wfr[0] = wp[0]; *(float4*)&wfr[4] = wp[1];
    }
    float bf = b_full[0];
    const ushort* a1base = att1 + (long long)ob * kP * kA + lane * 8;
    for (int p0 = 0; p0 < kP; p0 += 8) {
        int p = p0 + wave;
        if (p < kP) {
            uint4 u = *(const uint4*)(a1base + (long long)p * kA);
            const unsigned* uw = (const unsigned*)&u;
            float s = 0.f;
            #pragma unroll
            for (int j = 0; j < 4; j++) {
                unsigned x = uw[j];
                float v0 = b2f((ushort)(x & 0xffffu)) + a2r[2 * j];
                float v1 = b2f((ushort)(x >> 16))     + a2r[2 * j + 1];
                s += fmaxf(v0, 0.f) * wfr[2 * j] + fmaxf(v1, 0.f) * wfr[2 * j + 1];
            }
            #pragma unroll
            for (int off = 32; off; off >>= 1) s += __shfl_down(s, off);
            if (lane == 0) es[p] = s + bf;
        }
    }
    __syncthreads();
    float e = (tid < kP) ? es[tid] : -1e30f;
    float wm = e;
    for (int off = 32; off; off >>= 1) wm = fmaxf(wm, __shfl_down(wm, off));
    if (lane == 0) red1[wave] = wm;
    __syncthreads();
    float gm = red1[0];
    #pragma unroll
    for (int i = 1; i < 8; i++) gm = fmaxf(gm, red1[i]);
    float ex = (tid < kP) ? expf(e - gm) : 0.f;
    float sw = ex;
    for (int off = 32; off; off >>= 1) sw += __shfl_down(sw, off);
    if (lane == 0) red2[wave] = sw;
    __syncthreads();
    float S = red2[0];
    #pragma unroll
    for (int i = 1; i < 8; i++) S += red2[i];
    if (tid < kP) {
        float a = ex / S;
        alpha[b * kP + tid] = a;
        alphas_out[((long long)b * kT + t) * kP + tid] = (t < declen[b]) ? a : 0.f;
    }
}

// ---------------------------------------------------------------------------
// Fused awe + build_x. grid (5, kB), 128 threads:
//   blockIdx.x in [0,4): awe cols [x*512, x*512+512), 4 per thread
//   blockIdx.x == 4:     emb + style cols [0,640)
// ---------------------------------------------------------------------------
__global__ __launch_bounds__(128) void awe_buildx_kernel(
    const float* __restrict__ encf, const ushort* __restrict__ encb, int use_bf,
    const int* __restrict__ sort_ind, const float* __restrict__ alpha,
    const float* __restrict__ gate, const int* __restrict__ caps_i, int t,
    const float* __restrict__ emb_table, const float* __restrict__ style,
    float* __restrict__ xh)
{
    int b = blockIdx.y;
    int tid = threadIdx.x;
    if (blockIdx.x == 4) {
        int tok = caps_i[b * kTCAP + t];
        for (int i = tid; i < 160; i += 128) {
            float4 v;
            if (i < 128) v = *(const float4*)(emb_table + (long long)tok * kEMB + i * 4);
            else         v = *(const float4*)(style + b * kLC + (i - 128) * 4);
            *(float4*)(xh + (long long)b * kXH + i * 4) = v;
        }
        return;
    }
    __shared__ float al[kP];
    for (int i = tid; i < kP; i += 128) al[i] = alpha[b * kP + i];
    __syncthreads();
    int c0 = blockIdx.x * 512 + tid * 4;         // e2 base in [0, 2048)
    float a0 = 0.f, a1 = 0.f, a2 = 0.f, a3 = 0.f;
    if (use_bf) {
        const ushort* base = encb + (long long)b * kP * kE + c0;
        #pragma unroll 4
        for (int p = 0; p < kP; p++) {
            uint2 u = *(const uint2*)(base + (long long)p * kE);
            float ap = al[p];
            a0 += b2f((ushort)(u.x & 0xffffu)) * ap;
            a1 += b2f((ushort)(u.x >> 16))     * ap;
            a2 += b2f((ushort)(u.y & 0xffffu)) * ap;
            a3 += b2f((ushort)(u.y >> 16))     * ap;
        }
    } else {
        const float* base = encf + (long long)sort_ind[b] * kP * kE + c0;
        #pragma unroll 4
        for (int p = 0; p < kP; p++) {
            float4 v = *(const float4*)(base + (long long)p * kE);
            float ap = al[p];
            a0 += v.x * ap; a1 += v.y * ap; a2 += v.z * ap; a3 += v.w * ap;
        }
    }
    float4 g = *(const float4*)(gate + (long long)b * kE + c0);
    float4 o;
    o.x = a0 / (1.f + expf(-g.x));
    o.y = a1 / (1.f + expf(-g.y));
    o.z = a2 / (1.f + expf(-g.z));
    o.w = a3 / (1.f + expf(-g.w));
    *(float4*)(xh + (long long)b * kXH + kEMB + kLC + c0) = o;
}

// ---------------------------------------------------------------------------
// LSTM cell; reduces KZ split-K partials + gbias. h -> xh[:,2688:3200] and
// Hbuf[t][b][:] (bf16) for the batched end-of-loop preds GEMM.
// ---------------------------------------------------------------------------
__global__ __launch_bounds__(256) void lstm_cell_kernel(
    const float* __restrict__ gpart, const float* __restrict__ gbias,
    float* __restrict__ xh, float* __restrict__ c,
    ushort* __restrict__ Hbuf, int t)
{
    int idx = blockIdx.x * 256 + threadIdx.x;   // b*512 + d
    int b = idx >> 9, d = idx & 511;
    float gi = gbias[d], gf = gbias[kD + d], gg = gbias[2 * kD + d], go = gbias[3 * kD + d];
    const float* g = gpart + (long long)b * 4 * kD + d;
    #pragma unroll
    for (int z = 0; z < KZ; z++) {
        const float* gz = g + (long long)z * kB * 4 * kD;
        gi += gz[0]; gf += gz[kD]; gg += gz[2 * kD]; go += gz[3 * kD];
    }
    float si = 1.f / (1.f + expf(-gi));
    float sf = 1.f / (1.f + expf(-gf));
    float so = 1.f / (1.f + expf(-go));
    float cn = sf * c[idx] + si * tanhf(gg);
    float hn = so * tanhf(cn);
    c[idx] = cn;
    xh[(long long)b * kXH + kX + d] = hn;
    Hbuf[((long long)t * kB + b) * kD + d] = f2b(hn);
}

// ---------------------------------------------------------------------------
extern "C" void kernel_launch(void* const* d_in, const int* in_sizes, int n_in,
                              void* d_out, int out_size, void* d_ws, size_t ws_size,
                              hipStream_t stream)
{
    const float* encoder_out  = (const float*)d_in[0];
    const int*   enc_caps     = (const int*)  d_in[1];
    const int*   cap_lengths  = (const int*)  d_in[2];
    const int*   length_class = (const int*)  d_in[3];
    const float* W_enc_att = (const float*)d_in[4];
    const float* b_enc_att = (const float*)d_in[5];
    const float* W_dec_att = (const float*)d_in[6];
    const float* b_dec_att = (const float*)d_in[7];
    const float* w_full_att = (const float*)d_in[8];
    const float* b_full_att = (const float*)d_in[9];
    const float* W_init_h = (const float*)d_in[10];
    const float* b_init_h = (const float*)d_in[11];
    const float* W_init_c = (const float*)d_in[12];
    const float* b_init_c = (const float*)d_in[13];
    const float* W_fbeta  = (const float*)d_in[14];
    const float* b_fbeta  = (const float*)d_in[15];
    const float* emb_table = (const float*)d_in[16];
    const float* lc_table  = (const float*)d_in[17];
    const float* W_fc = (const float*)d_in[18];
    const float* b_fc = (const float*)d_in[19];
    const float* W_ih = (const float*)d_in[20];
    const float* b_ih = (const float*)d_in[21];
    const float* W_hh = (const float*)d_in[22];
    const float* b_hh = (const float*)d_in[23];

    // Output layout (flat float32, reference return order)
    float* out = (float*)d_out;
    float* o_pred    = out;                                  // B*T*V
    float* o_caps    = out + (long long)kB * kT * kV;
    float* o_declen  = o_caps + kB * kTCAP;
    float* o_alpha   = o_declen + kB;
    float* o_sortind = o_alpha + (long long)kB * kT * kP;

    // Workspace carve: f32 region, bf16 region, int region.
    float* w = (float*)d_ws;
    float* xh       = w; w += kB * kXH;
    float* c        = w; w += kB * kD;
    float* att2     = w; w += kB * kA;
    float* gate     = w; w += kB * kE;
    float* mean_enc = w; w += kB * kE;
    float* gpart    = w; w += (long long)kB * 4 * kD * KZ;  // split-K partials
    float* alpha    = w; w += kB * kP;
    float* style    = w; w += kB * kLC;
    float* bias3    = w; w += kN3;
    float* bias_hc  = w; w += 1024;
    float* gbias    = w; w += 2048;
    ushort* us = (ushort*)w;
    ushort* att1_bf  = us; us += (long long)kB * kP * kA;   // 12.85M
    ushort* WencT    = us; us += (long long)kA * kE;        // [512][2048]
    ushort* WhcT     = us; us += (long long)1024 * kE;      // [1024][2048]
    ushort* WcatT    = us; us += (long long)(4 * kD) * kXH; // [2048][3200]
    ushort* Wcat3T   = us; us += (long long)kN3 * kD;       // [12560][512]
    ushort* Hbuf     = us; us += (long long)kT * kB * kD;   // [25*128][512] bf16
    int* iw = (int*)us;
    int* sort_ind = iw; iw += kB;
    int* declen   = iw; iw += kB;
    int* caps_i   = iw; iw += kB * kTCAP;
    ushort* enc_bf = (ushort*)(iw + kB);  // optional, 102.8 MB

    // Decide enc-bf16 path by workspace headroom (ws_size is call-invariant).
    size_t need_with_enc = ((char*)(enc_bf + (long long)kB * kP * kE)) - (char*)d_ws;
    int use_encbf = (ws_size >= need_with_enc) ? 1 : 0;

    sort_setup<<<1, 128, 0, stream>>>(cap_lengths, enc_caps, length_class, lc_table,
        sort_ind, declen, caps_i, style, o_caps, o_declen, o_sortind);

    // One-time weight prep: transpose-convert all B matrices to [N][K] bf16.
    auto tc = [&](const float* s, int ldsrc, int Kr, int Nc, ushort* d, long long ldd) {
        tcvt_kernel<<<dim3((Nc + 31) / 32, (Kr + 31) / 32), 256, 0, stream>>>(
            s, ldsrc, Kr, Nc, d, ldd);
    };
    tc(W_enc_att, kA, kE, kA, WencT, kE);                       // [512][2048]
    tc(W_init_h,  kD, kE, kD, WhcT, kE);                        // rows 0..512
    tc(W_init_c,  kD, kE, kD, WhcT + (long long)kD * kE, kE);   // rows 512..1024
    tc(W_ih, 4 * kD, kX, 4 * kD, WcatT, kXH);                   // k in [0,2688)
    tc(W_hh, 4 * kD, kD, 4 * kD, WcatT + kX, kXH);              // k in [2688,3200)
    tc(W_fc,      kV, kD, kV, Wcat3T, kD);                      // rows 0..10000
    tc(W_dec_att, kA, kD, kA, Wcat3T + (long long)kV * kD, kD); // rows 10000..10512
    tc(W_fbeta,   kE, kD, kE, Wcat3T + (long long)(kV + kA) * kD, kD);
    bias_setup_kernel<<<(kN3 + 1024 + 2048 + 255) / 256, 256, 0, stream>>>(
        b_fc, b_dec_att, b_fbeta, b_init_h, b_init_c, b_ih, b_hh, bias3, bias_hc, gbias);

    if (use_encbf) {
        enc_cvt_kernel<<<(unsigned)(((long long)kB * kP * kE / 4 + 255) / 256), 256, 0, stream>>>(
            encoder_out, sort_ind, enc_bf);
    }
    mean_enc_kernel<<<(kB * kE) / 256, 256, 0, stream>>>(
        encoder_out, enc_bf, use_encbf, sort_ind, mean_enc);

    auto g2 = [](int M, int N) { return dim3((unsigned)((N + 127) / 128), (unsigned)(M / 64)); };

    // h0 | c0 in one GEMM (split epilogue)
    gemm2<<<g2(kB, 1024), 256, 0, stream>>>(mean_enc, kE, 0, WhcT, kE, bias_hc,
        xh + kX, kXH, 0, 512, c, kD, kBIG, nullptr, 0, nullptr, 0, 0,
        kB, 1024, kE, 0);

    // att1 (bf16) = enc_sorted @ W_enc_att + b_enc_att
    if (use_encbf) {
        gemm2<<<g2(kB * kP, kA), 256, 0, stream>>>(enc_bf, kE, 1, WencT, kE, b_enc_att,
            att1_bf, kA, 1, kBIG, nullptr, 0, kBIG, nullptr, 0, nullptr, 0, 0,
            kB * kP, kA, kE, 0);
    } else {
        // A = unsorted f32 enc; att1 rows are then in ORIGINAL order and the
        // softmax kernel gathers rows via smap = sort_ind.
        gemm2<<<g2(kB * kP, kA), 256, 0, stream>>>(encoder_out, kE, 0, WencT, kE, b_enc_att,
            att1_bf, kA, 1, kBIG, nullptr, 0, kBIG, nullptr, 0, nullptr, 0, 0,
            kB * kP, kA, kE, 0);
    }

    // pre-loop: att2/gate for t=0 from h0
    gemm2<<<g2(kB, kA + kE), 256, 0, stream>>>(xh + kX, kXH, 0,
        Wcat3T + (long long)kV * kD, kD, bias3 + kV, att2, kA, 0,
        kA, gate, kE, kBIG, nullptr, 0, nullptr, 0, 0, kB, kA + kE, kD, 0);

    const int* smap = use_encbf ? nullptr : sort_ind;
    for (int t = 0; t < kT; t++) {
        attn_softmax_kernel<<<kB, 512, 0, stream>>>(att1_bf, att2, w_full_att,
            b_full_att, alpha, o_alpha, declen, t, smap);
        awe_buildx_kernel<<<dim3(5, kB), 128, 0, stream>>>(
            encoder_out, enc_bf, use_encbf, sort_ind, alpha, gate, caps_i, t,
            emb_table, style, xh);
        // gates partials via split-K (KZ slices of K=3200)
        gemm2<<<dim3((4 * kD + 127) / 128, kB / 64, KZ), 256, 0, stream>>>(
            xh, kXH, 0, WcatT, kXH, nullptr,
            gpart, 4 * kD, 0, kBIG, nullptr, 0, kBIG, nullptr, 0, nullptr, 0, 0,
            kB, 4 * kD, kXH, (long long)kB * 4 * kD);
        lstm_cell_kernel<<<(kB * kD) / 256, 256, 0, stream>>>(gpart, gbias, xh, c, Hbuf, t);
        // att2_{t+1} | gate_{t+1} only (preds batched after the loop)
        gemm2<<<g2(kB, kA + kE), 256, 0, stream>>>(xh + kX, kXH, 0,
            Wcat3T + (long long)kV * kD, kD, bias3 + kV, att2, kA, 0,
            kA, gate, kE, kBIG, nullptr, 0, nullptr, 0, 0, kB, kA + kE, kD, 0);
    }

    // Batched preds: [kT*kB, kV] = Hbuf @ W_fc + b_fc, masked by declen.
    gemm2<<<g2(kT * kB, kV), 256, 0, stream>>>(Hbuf, kD, 1, Wcat3T, kD, bias3,
        o_pred, kV, 0, kV, nullptr, 0, kBIG, nullptr, 0, declen, 0, 1,
        kT * kB, kV, kD, 0);
}

// Round 3
// 2736.969 us; speedup vs baseline: 2.4460x; 1.0351x over previous
//
#include <hip/hip_runtime.h>
#include <math.h>

// Problem constants
constexpr int kB   = 128;
constexpr int kP   = 196;     // 14*14
constexpr int kE   = 2048;
constexpr int kA   = 512;
constexpr int kEMB = 512;
constexpr int kD   = 512;
constexpr int kV   = 10000;
constexpr int kLC  = 128;
constexpr int kTCAP= 26;
constexpr int kT   = 25;
constexpr int kX   = kEMB + kLC + kE;   // 2688
constexpr int kXH  = kX + kD;           // 3200 = [x | h]
constexpr int kN3  = kV + kA + kE;      // 12560 = [W_fc | W_dec_att | W_fbeta] cols
constexpr int kBIG = 1 << 30;
constexpr int KZ   = 5;                 // split-K factor for gates GEMM (3200/5 = 640)

typedef __attribute__((ext_vector_type(8))) short bf8;
typedef __attribute__((ext_vector_type(4))) float f4;

__device__ inline float b2f(ushort u) { return __uint_as_float(((unsigned)u) << 16); }
__device__ inline ushort f2b(float f) {  // round-to-nearest-even
    unsigned u = __float_as_uint(f);
    return (ushort)((u + 0x7fffu + ((u >> 16) & 1u)) >> 16);
}

// XOR-swizzled LDS short-index for GEMM tiles (row stride 32 shorts = 64B).
#define SWZ(r, k) ((((r) * 32) + (k)) ^ (((r) & 7) << 3))

// ---------------------------------------------------------------------------
// Sort + gathers (single block, 128 threads). Stable descending argsort.
// ---------------------------------------------------------------------------
__global__ __launch_bounds__(128) void sort_setup(
    const int* __restrict__ caplen, const int* __restrict__ caps_in,
    const int* __restrict__ lclass, const float* __restrict__ lc_table,
    int* __restrict__ sort_ind, int* __restrict__ declen, int* __restrict__ caps_i,
    float* __restrict__ style,
    float* __restrict__ out_caps, float* __restrict__ out_declen,
    float* __restrict__ out_sortind)
{
    __shared__ int lens[kB];
    __shared__ int sind[kB];
    int i = threadIdx.x;
    lens[i] = caplen[i];
    __syncthreads();
    int li = lens[i];
    int r = 0;
    for (int j = 0; j < kB; j++) {
        int lj = lens[j];
        if (lj > li || (lj == li && j < i)) r++;
    }
    sind[r] = i;
    sort_ind[r] = i;
    out_sortind[r] = (float)i;
    __syncthreads();
    int orig = sind[i];
    int dl = lens[orig] - 1;
    declen[i] = dl;
    out_declen[i] = (float)dl;
    for (int t = 0; t < kTCAP; t++) {
        int cv = caps_in[orig * kTCAP + t];
        caps_i[i * kTCAP + t] = cv;
        out_caps[i * kTCAP + t] = (float)cv;
    }
    int lcl = lclass[orig];
    for (int k = 0; k < kLC; k++) style[i * kLC + k] = lc_table[lcl * kLC + k];
}

// ---------------------------------------------------------------------------
// Transpose-convert: dst[n][k] (bf16, row stride ldd) = src[k][n] (f32, ldsrc)
// ---------------------------------------------------------------------------
__global__ __launch_bounds__(256) void tcvt_kernel(
    const float* __restrict__ src, int ldsrc, int K, int N,
    ushort* __restrict__ dst, long long ldd)
{
    __shared__ float tile[32][33];
    int k0 = blockIdx.y * 32, n0 = blockIdx.x * 32;
    int tx = threadIdx.x & 31, ty = threadIdx.x >> 5;   // 32 x 8
    #pragma unroll
    for (int j = 0; j < 4; j++) {
        int k = k0 + ty + j * 8, n = n0 + tx;
        tile[ty + j * 8][tx] = (k < K && n < N) ? src[(long long)k * ldsrc + n] : 0.f;
    }
    __syncthreads();
    #pragma unroll
    for (int j = 0; j < 4; j++) {
        int n = n0 + ty + j * 8, k = k0 + tx;
        if (n < N && k < K) dst[(long long)n * ldd + k] = f2b(tile[tx][ty + j * 8]);
    }
}

// bias3 = [b_fc | b_dec | b_fbeta]; bias_hc = [b_ih0 | b_ic0]; gbias = b_ih+b_hh
__global__ __launch_bounds__(256) void bias_setup_kernel(
    const float* __restrict__ b_fc, const float* __restrict__ b_dec,
    const float* __restrict__ b_fb, const float* __restrict__ b_ih0,
    const float* __restrict__ b_ic0, const float* __restrict__ b_ih,
    const float* __restrict__ b_hh,
    float* __restrict__ bias3, float* __restrict__ bias_hc, float* __restrict__ gbias)
{
    int idx = blockIdx.x * 256 + threadIdx.x;
    if (idx < kN3) {
        float v;
        if (idx < kV) v = b_fc[idx];
        else if (idx < kV + kA) v = b_dec[idx - kV];
        else v = b_fb[idx - kV - kA];
        bias3[idx] = v;
    } else if (idx < kN3 + 1024) {
        int i = idx - kN3;
        bias_hc[i] = (i < 512) ? b_ih0[i] : b_ic0[i - 512];
    } else if (idx < kN3 + 1024 + 2048) {
        int i = idx - kN3 - 1024;
        gbias[i] = b_ih[i] + b_hh[i];
    }
}

// enc (sorted) -> bf16: enc_bf[b][p][e] = bf16(enc[sort_ind[b]][p][e])
__global__ __launch_bounds__(256) void enc_cvt_kernel(
    const float* __restrict__ enc, const int* __restrict__ sort_ind,
    ushort* __restrict__ enc_bf)
{
    long long idx4 = (long long)blockIdx.x * 256 + threadIdx.x;
    if (idx4 >= (long long)kB * kP * kE / 4) return;
    int r = (int)(idx4 >> 9);          // dst row (b*196+p), 512 chunks/row
    int cc = ((int)idx4 & 511) * 4;
    int b = r / kP, p = r - b * kP;
    long long srow = (long long)sort_ind[b] * kP + p;
    float4 v = *(const float4*)(enc + srow * kE + cc);
    ushort4 o; o.x = f2b(v.x); o.y = f2b(v.y); o.z = f2b(v.z); o.w = f2b(v.w);
    *(ushort4*)(enc_bf + (long long)r * kE + cc) = o;
}

// mean over p (dual source: bf16 sorted, or f32 unsorted + sort_ind)
__global__ __launch_bounds__(256) void mean_enc_kernel(
    const float* __restrict__ encf, const ushort* __restrict__ encb, int use_bf,
    const int* __restrict__ sort_ind, float* __restrict__ me)
{
    int idx = blockIdx.x * 256 + threadIdx.x;   // b*2048 + e
    int b = idx >> 11, e = idx & 2047;
    float s = 0.f;
    if (use_bf) {
        const ushort* base = encb + (long long)b * kP * kE + e;
        #pragma unroll 4
        for (int p = 0; p < kP; p++) s += b2f(base[(long long)p * kE]);
    } else {
        const float* base = encf + (long long)sort_ind[b] * kP * kE + e;
        #pragma unroll 4
        for (int p = 0; p < kP; p++) s += base[(long long)p * kE];
    }
    me[idx] = s * (1.0f / 196.0f);
}

// ---------------------------------------------------------------------------
// bf16 MFMA GEMM v4 (64x128 tile): C = A[M,K] @ Bt[N][K]^T + bias.
// Used for the small/medium GEMMs (h0c0, att2|gate, gates split-K, fallback).
// ---------------------------------------------------------------------------
__global__ __launch_bounds__(256) void gemm2(
    const void* __restrict__ Am, int lda, int a_bf16,
    const ushort* __restrict__ Bt, int ldbt,
    const float* __restrict__ bias,
    void* __restrict__ out1, long long ldc1, int c1_bf16,
    int split1, float* __restrict__ out2, long long ldc2,
    int split2, float* __restrict__ out3, long long ldc3,
    const int* __restrict__ declen, int t, int pred_mode,
    int M, int N, int K, long long zstride)
{
    __shared__ short As[64 * 32];    // swizzled, 64B row stride
    __shared__ short Bs[128 * 32];
    int tid = threadIdx.x;
    int lane = tid & 63, w = tid >> 6, quad = lane >> 4, l16 = lane & 15;
    int m0 = blockIdx.y * 64, n0 = blockIdx.x * 128;

    f4 acc[8];
    #pragma unroll
    for (int i = 0; i < 8; i++) acc[i] = (f4){0.f, 0.f, 0.f, 0.f};

    int a_r = tid >> 2;
    int a_kc = (tid & 3) * 8;
    long long a_row = m0 + a_r;
    const float*  a_srcf = (const float*)Am  + a_row * (long long)lda + a_kc;
    const ushort* a_srcb = (const ushort*)Am + a_row * (long long)lda + a_kc;

    int b_r = tid >> 1;
    int b_kc = (tid & 1) * 16;
    bool bvalid = (n0 + b_r) < N;
    const ushort* b_src = Bt + (long long)(n0 + b_r) * ldbt + b_kc;

    int kpb = K / (int)gridDim.z;
    int kbeg = (int)blockIdx.z * kpb, kend = kbeg + kpb;

    float4 af0 = make_float4(0.f, 0.f, 0.f, 0.f), af1 = af0;
    uint4 au, bu0, bu1;
    au.x = au.y = au.z = au.w = 0u; bu0 = au; bu1 = au;

    if (a_bf16) au = *(const uint4*)(a_srcb + kbeg);
    else { af0 = *(const float4*)(a_srcf + kbeg); af1 = *(const float4*)(a_srcf + kbeg + 4); }
    if (bvalid) { bu0 = *(const uint4*)(b_src + kbeg); bu1 = *(const uint4*)(b_src + kbeg + 8); }

    for (int k0 = kbeg; k0 < kend; k0 += 32) {
        __syncthreads();
        if (a_bf16) {
            *(uint4*)&As[SWZ(a_r, a_kc)] = au;
        } else {
            uint4 pk; ushort* pp = (ushort*)&pk;
            pp[0] = f2b(af0.x); pp[1] = f2b(af0.y); pp[2] = f2b(af0.z); pp[3] = f2b(af0.w);
            pp[4] = f2b(af1.x); pp[5] = f2b(af1.y); pp[6] = f2b(af1.z); pp[7] = f2b(af1.w);
            *(uint4*)&As[SWZ(a_r, a_kc)] = pk;
        }
        *(uint4*)&Bs[SWZ(b_r, b_kc)]     = bu0;
        *(uint4*)&Bs[SWZ(b_r, b_kc + 8)] = bu1;
        int kn = k0 + 32;
        if (kn < kend) {
            if (a_bf16) au = *(const uint4*)(a_srcb + kn);
            else { af0 = *(const float4*)(a_srcf + kn); af1 = *(const float4*)(a_srcf + kn + 4); }
            if (bvalid) { bu0 = *(const uint4*)(b_src + kn); bu1 = *(const uint4*)(b_src + kn + 8); }
        }
        __syncthreads();
        bf8 a = *(const bf8*)&As[SWZ(w * 16 + l16, quad * 8)];
        #pragma unroll
        for (int nt = 0; nt < 8; nt++) {
            bf8 b = *(const bf8*)&Bs[SWZ(nt * 16 + l16, quad * 8)];
            acc[nt] = __builtin_amdgcn_mfma_f32_16x16x32_bf16(a, b, acc[nt], 0, 0, 0);
        }
    }

    long long zoff = (long long)blockIdx.z * zstride;
    #pragma unroll
    for (int nt = 0; nt < 8; nt++) {
        int cn = n0 + nt * 16 + l16;
        if (cn >= N) continue;
        float bv = bias ? bias[cn] : 0.f;
        #pragma unroll
        for (int reg = 0; reg < 4; reg++) {
            int rr = m0 + w * 16 + quad * 4 + reg;
            float v = acc[nt][reg] + bv;
            if (cn < split1) {
                long long idx;
                if (pred_mode) {
                    int bb = rr & 127, tt = rr >> 7;
                    if (tt >= declen[bb]) v = 0.f;
                    idx = ((long long)bb * kT + tt) * ldc1 + cn;
                } else {
                    if (declen && t >= declen[rr]) v = 0.f;
                    idx = (long long)rr * ldc1 + cn + zoff;
                }
                if (c1_bf16) ((ushort*)out1)[idx] = f2b(v);
                else         ((float*)out1)[idx] = v;
            } else if (cn < split2) {
                out2[(long long)rr * ldc2 + (cn - split1)] = v;
            } else {
                out3[(long long)rr * ldc3 + (cn - split2)] = v;
            }
        }
    }
}

// ---------------------------------------------------------------------------
// gemm_big: 128x128 tile, 4 waves in 2x2 grid, 4x4 fragments/wave (m97-style).
// A bf16 [M][lda], Bt bf16 [N][ldbt]. out1 f32 or bf16.
// pred_mode: row rr = t*128 + b, write ((b*kT+t)*ldc1 + cn), mask t>=declen[b];
// upper-half waves skip compute when their whole b-range is masked.
// Bijective XCD-chunked block swizzle on the flattened grid id.
// M % 128 == 0, K % 32 == 0.
// ---------------------------------------------------------------------------
__global__ __launch_bounds__(256) void gemm_big(
    const ushort* __restrict__ A, int lda,
    const ushort* __restrict__ Bt, int ldbt,
    const float* __restrict__ bias,
    void* __restrict__ out1, long long ldc1, int c1_bf16,
    const int* __restrict__ declen, int pred_mode,
    int M, int N, int K)
{
    __shared__ short As[128 * 32];
    __shared__ short Bs[128 * 32];
    // XCD-chunked bijective swizzle (m204)
    unsigned nwg = gridDim.x * gridDim.y;
    unsigned lin = blockIdx.y * gridDim.x + blockIdx.x;
    unsigned q = nwg >> 3, rm = nwg & 7;
    unsigned xcd = lin & 7, loc = lin >> 3;
    unsigned swz = (xcd < rm ? xcd * (q + 1) : rm * (q + 1) + (xcd - rm) * q) + loc;
    int bx = (int)(swz % gridDim.x), by = (int)(swz / gridDim.x);
    int m0 = by * 128, n0 = bx * 128;

    int tid = threadIdx.x;
    int lane = tid & 63, w = tid >> 6, quad = lane >> 4, l16 = lane & 15;
    int wr = w >> 1, wc = w & 1;

    f4 acc[4][4];
    #pragma unroll
    for (int m = 0; m < 4; m++)
        #pragma unroll
        for (int n = 0; n < 4; n++) acc[m][n] = (f4){0.f, 0.f, 0.f, 0.f};

    bool wact = true;
    if (pred_mode) wact = declen[wr * 64] > (m0 >> 7);

    // staging: 2 threads per row, 16 shorts each
    int s_r = tid >> 1, s_kc = (tid & 1) * 16;
    const ushort* a_src = A + (long long)(m0 + s_r) * lda + s_kc;
    bool bval = (n0 + s_r) < N;
    const ushort* b_src = Bt + (long long)(n0 + s_r) * ldbt + s_kc;

    uint4 au0, au1, bu0, bu1;
    au0.x = au0.y = au0.z = au0.w = 0u; au1 = au0; bu0 = au0; bu1 = au0;
    au0 = *(const uint4*)(a_src);
    au1 = *(const uint4*)(a_src + 8);
    if (bval) { bu0 = *(const uint4*)(b_src); bu1 = *(const uint4*)(b_src + 8); }

    for (int k0 = 0; k0 < K; k0 += 32) {
        __syncthreads();
        *(uint4*)&As[SWZ(s_r, s_kc)]     = au0;
        *(uint4*)&As[SWZ(s_r, s_kc + 8)] = au1;
        *(uint4*)&Bs[SWZ(s_r, s_kc)]     = bu0;
        *(uint4*)&Bs[SWZ(s_r, s_kc + 8)] = bu1;
        int kn = k0 + 32;
        if (kn < K) {
            au0 = *(const uint4*)(a_src + kn);
            au1 = *(const uint4*)(a_src + kn + 8);
            if (bval) { bu0 = *(const uint4*)(b_src + kn); bu1 = *(const uint4*)(b_src + kn + 8); }
        }
        __syncthreads();
        if (wact) {
            bf8 af[4], bfr[4];
            #pragma unroll
            for (int m = 0; m < 4; m++)
                af[m] = *(const bf8*)&As[SWZ(wr * 64 + m * 16 + l16, quad * 8)];
            #pragma unroll
            for (int n = 0; n < 4; n++)
                bfr[n] = *(const bf8*)&Bs[SWZ(wc * 64 + n * 16 + l16, quad * 8)];
            #pragma unroll
            for (int m = 0; m < 4; m++)
                #pragma unroll
                for (int n = 0; n < 4; n++)
                    acc[m][n] = __builtin_amdgcn_mfma_f32_16x16x32_bf16(af[m], bfr[n], acc[m][n], 0, 0, 0);
        }
    }

    #pragma unroll
    for (int n = 0; n < 4; n++) {
        int cn = n0 + wc * 64 + n * 16 + l16;
        if (cn >= N) continue;
        float bv = bias ? bias[cn] : 0.f;
        #pragma unroll
        for (int m = 0; m < 4; m++) {
            #pragma unroll
            for (int reg = 0; reg < 4; reg++) {
                int rr = m0 + wr * 64 + m * 16 + quad * 4 + reg;
                float v = acc[m][n][reg] + bv;
                long long idx;
                if (pred_mode) {
                    int bb = rr & 127, tt = rr >> 7;
                    if (tt >= declen[bb]) v = 0.f;
                    idx = ((long long)bb * kT + tt) * ldc1 + cn;
                } else {
                    idx = (long long)rr * ldc1 + cn;
                }
                if (c1_bf16) ((ushort*)out1)[idx] = f2b(v);
                else         ((float*)out1)[idx] = v;
            }
        }
    }
}

// ---------------------------------------------------------------------------
// Fused attention: energies + softmax + awe + build_x. grid (2, kB), 512 thr.
// Both halves compute the (cheap) softmax redundantly; half x computes awe
// columns [x*1024, x*1024+1024). half 0 writes alphas_out; half 1 writes
// emb/style columns. Energy loads 4-deep batched for ILP.
// ---------------------------------------------------------------------------
__global__ __launch_bounds__(512) void attn_awe_kernel(
    const ushort* __restrict__ att1, const float* __restrict__ att2,
    const float* __restrict__ w_full, const float* __restrict__ b_full,
    const float* __restrict__ encf, const ushort* __restrict__ encb, int use_bf,
    const int* __restrict__ sort_ind, const float* __restrict__ gate,
    const int* __restrict__ caps_i, int t,
    const float* __restrict__ emb_table, const float* __restrict__ style,
    float* __restrict__ xh, float* __restrict__ alphas_out,
    const int* __restrict__ declen, const int* __restrict__ smap)
{
    int b = blockIdx.y;
    int half = blockIdx.x;
    int ob = smap ? smap[b] : b;
    __shared__ float al[kP];
    __shared__ float red1[8], red2[8];
    int tid = threadIdx.x, wave = tid >> 6, lane = tid & 63;

    // --- energies: wave handles p = wave + 8*i, 4-deep load batching ---
    float a2r[8], wfr[8];
    {
        const float4* ap = (const float4*)(att2 + (long long)b * kA + lane * 8);
        *(float4*)&a2r[0] = ap[0]; *(float4*)&a2r[4] = ap[1];
        const float4* wp = (const float4*)(w_full + lane * 8);
        *(float4*)&wfr[0] = wp[0]; *(float4*)&wfr[4] = wp[1];
    }
    float bfull = b_full[0];
    const ushort* a1 = att1 + (long long)ob * kP * kA + lane * 8;
    for (int i0 = 0; i0 < 25; i0 += 4) {
        uint4 u[4]; int pv[4];
        #pragma unroll
        for (int j = 0; j < 4; j++) {
            int i = i0 + j, p = wave + 8 * i;
            pv[j] = (i < 25 && p < kP) ? p : -1;
            if (pv[j] >= 0) u[j] = *(const uint4*)(a1 + (long long)pv[j] * kA);
        }
        #pragma unroll
        for (int j = 0; j < 4; j++) {
            if (pv[j] < 0) continue;
            const unsigned* uw = (const unsigned*)&u[j];
            float s = 0.f;
            #pragma unroll
            for (int q = 0; q < 4; q++) {
                unsigned x = uw[q];
                float v0 = b2f((ushort)(x & 0xffffu)) + a2r[2 * q];
                float v1 = b2f((ushort)(x >> 16))     + a2r[2 * q + 1];
                s += fmaxf(v0, 0.f) * wfr[2 * q] + fmaxf(v1, 0.f) * wfr[2 * q + 1];
            }
            #pragma unroll
            for (int off = 32; off; off >>= 1) s += __shfl_down(s, off);
            if (lane == 0) al[pv[j]] = s + bfull;
        }
    }
    __syncthreads();

    // --- softmax over al[0..195] ---
    float e = (tid < kP) ? al[tid] : -1e30f;
    float wm = e;
    for (int off = 32; off; off >>= 1) wm = fmaxf(wm, __shfl_down(wm, off));
    if (lane == 0) red1[wave] = wm;
    __syncthreads();
    float gm = red1[0];
    #pragma unroll
    for (int i = 1; i < 8; i++) gm = fmaxf(gm, red1[i]);
    float ex = (tid < kP) ? expf(e - gm) : 0.f;
    float sw = ex;
    for (int off = 32; off; off >>= 1) sw += __shfl_down(sw, off);
    if (lane == 0) red2[wave] = sw;
    __syncthreads();
    float S = red2[0];
    #pragma unroll
    for (int i = 1; i < 8; i++) S += red2[i];
    float a = ex / S;
    __syncthreads();            // everyone done reading al as energies
    if (tid < kP) {
        al[tid] = a;
        if (half == 0)
            alphas_out[((long long)b * kT + t) * kP + tid] = (t < declen[b]) ? a : 0.f;
    }
    __syncthreads();

    // --- emb/style (half 1 only; independent of alpha) ---
    if (half == 1 && tid < 160) {
        int tok = caps_i[b * kTCAP + t];
        float4 v;
        if (tid < 128) v = *(const float4*)(emb_table + (long long)tok * kEMB + tid * 4);
        else           v = *(const float4*)(style + b * kLC + (tid - 128) * 4);
        *(float4*)(xh + (long long)b * kXH + tid * 4) = v;
    }

    // --- awe: 512 threads x 2 cols in this half's 1024-col range ---
    int c0 = half * 1024 + tid * 2;
    float s0 = 0.f, s1 = 0.f;
    if (use_bf) {
        const ushort* base = encb + (long long)b * kP * kE + c0;
        #pragma unroll 4
        for (int p = 0; p < kP; p++) {
            unsigned uu = *(const unsigned*)(base + (long long)p * kE);
            float ap = al[p];
            s0 += b2f((ushort)(uu & 0xffffu)) * ap;
            s1 += b2f((ushort)(uu >> 16))     * ap;
        }
    } else {
        const float* base = encf + (long long)sort_ind[b] * kP * kE + c0;
        #pragma unroll 4
        for (int p = 0; p < kP; p++) {
            float2 v = *(const float2*)(base + (long long)p * kE);
            float ap = al[p];
            s0 += v.x * ap; s1 += v.y * ap;
        }
    }
    float2 g = *(const float2*)(gate + (long long)b * kE + c0);
    float2 o;
    o.x = s0 / (1.f + expf(-g.x));
    o.y = s1 / (1.f + expf(-g.y));
    *(float2*)(xh + (long long)b * kXH + kEMB + kLC + c0) = o;
}

// ---------------------------------------------------------------------------
// LSTM cell; reduces KZ split-K partials + gbias. h -> xh[:,2688:3200] and
// Hbuf[t][b][:] (bf16) for the batched end-of-loop preds GEMM.
// ---------------------------------------------------------------------------
__global__ __launch_bounds__(256) void lstm_cell_kernel(
    const float* __restrict__ gpart, const float* __restrict__ gbias,
    float* __restrict__ xh, float* __restrict__ c,
    ushort* __restrict__ Hbuf, int t)
{
    int idx = blockIdx.x * 256 + threadIdx.x;   // b*512 + d
    int b = idx >> 9, d = idx & 511;
    float gi = gbias[d], gf = gbias[kD + d], gg = gbias[2 * kD + d], go = gbias[3 * kD + d];
    const float* g = gpart + (long long)b * 4 * kD + d;
    #pragma unroll
    for (int z = 0; z < KZ; z++) {
        const float* gz = g + (long long)z * kB * 4 * kD;
        gi += gz[0]; gf += gz[kD]; gg += gz[2 * kD]; go += gz[3 * kD];
    }
    float si = 1.f / (1.f + expf(-gi));
    float sf = 1.f / (1.f + expf(-gf));
    float so = 1.f / (1.f + expf(-go));
    float cn = sf * c[idx] + si * tanhf(gg);
    float hn = so * tanhf(cn);
    c[idx] = cn;
    xh[(long long)b * kXH + kX + d] = hn;
    Hbuf[((long long)t * kB + b) * kD + d] = f2b(hn);
}

// ---------------------------------------------------------------------------
extern "C" void kernel_launch(void* const* d_in, const int* in_sizes, int n_in,
                              void* d_out, int out_size, void* d_ws, size_t ws_size,
                              hipStream_t stream)
{
    const float* encoder_out  = (const float*)d_in[0];
    const int*   enc_caps     = (const int*)  d_in[1];
    const int*   cap_lengths  = (const int*)  d_in[2];
    const int*   length_class = (const int*)  d_in[3];
    const float* W_enc_att = (const float*)d_in[4];
    const float* b_enc_att = (const float*)d_in[5];
    const float* W_dec_att = (const float*)d_in[6];
    const float* b_dec_att = (const float*)d_in[7];
    const float* w_full_att = (const float*)d_in[8];
    const float* b_full_att = (const float*)d_in[9];
    const float* W_init_h = (const float*)d_in[10];
    const float* b_init_h = (const float*)d_in[11];
    const float* W_init_c = (const float*)d_in[12];
    const float* b_init_c = (const float*)d_in[13];
    const float* W_fbeta  = (const float*)d_in[14];
    const float* b_fbeta  = (const float*)d_in[15];
    const float* emb_table = (const float*)d_in[16];
    const float* lc_table  = (const float*)d_in[17];
    const float* W_fc = (const float*)d_in[18];
    const float* b_fc = (const float*)d_in[19];
    const float* W_ih = (const float*)d_in[20];
    const float* b_ih = (const float*)d_in[21];
    const float* W_hh = (const float*)d_in[22];
    const float* b_hh = (const float*)d_in[23];

    // Output layout (flat float32, reference return order)
    float* out = (float*)d_out;
    float* o_pred    = out;                                  // B*T*V
    float* o_caps    = out + (long long)kB * kT * kV;
    float* o_declen  = o_caps + kB * kTCAP;
    float* o_alpha   = o_declen + kB;
    float* o_sortind = o_alpha + (long long)kB * kT * kP;

    // Workspace carve: f32 region, bf16 region, int region.
    float* w = (float*)d_ws;
    float* xh       = w; w += kB * kXH;
    float* c        = w; w += kB * kD;
    float* att2     = w; w += kB * kA;
    float* gate     = w; w += kB * kE;
    float* mean_enc = w; w += kB * kE;
    float* gpart    = w; w += (long long)kB * 4 * kD * KZ;  // split-K partials
    float* style    = w; w += kB * kLC;
    float* bias3    = w; w += kN3;
    float* bias_hc  = w; w += 1024;
    float* gbias    = w; w += 2048;
    ushort* us = (ushort*)w;
    ushort* att1_bf  = us; us += (long long)kB * kP * kA;   // 12.85M
    ushort* WencT    = us; us += (long long)kA * kE;        // [512][2048]
    ushort* WhcT     = us; us += (long long)1024 * kE;      // [1024][2048]
    ushort* WcatT    = us; us += (long long)(4 * kD) * kXH; // [2048][3200]
    ushort* Wcat3T   = us; us += (long long)kN3 * kD;       // [12560][512]
    ushort* Hbuf     = us; us += (long long)kT * kB * kD;   // [25*128][512] bf16
    int* iw = (int*)us;
    int* sort_ind = iw; iw += kB;
    int* declen   = iw; iw += kB;
    int* caps_i   = iw; iw += kB * kTCAP;
    ushort* enc_bf = (ushort*)(iw + kB);  // optional, 102.8 MB

    // Decide enc-bf16 path by workspace headroom (ws_size is call-invariant).
    size_t need_with_enc = ((char*)(enc_bf + (long long)kB * kP * kE)) - (char*)d_ws;
    int use_encbf = (ws_size >= need_with_enc) ? 1 : 0;

    sort_setup<<<1, 128, 0, stream>>>(cap_lengths, enc_caps, length_class, lc_table,
        sort_ind, declen, caps_i, style, o_caps, o_declen, o_sortind);

    // One-time weight prep: transpose-convert all B matrices to [N][K] bf16.
    auto tc = [&](const float* s, int ldsrc, int Kr, int Nc, ushort* d, long long ldd) {
        tcvt_kernel<<<dim3((Nc + 31) / 32, (Kr + 31) / 32), 256, 0, stream>>>(
            s, ldsrc, Kr, Nc, d, ldd);
    };
    tc(W_enc_att, kA, kE, kA, WencT, kE);                       // [512][2048]
    tc(W_init_h,  kD, kE, kD, WhcT, kE);                        // rows 0..512
    tc(W_init_c,  kD, kE, kD, WhcT + (long long)kD * kE, kE);   // rows 512..1024
    tc(W_ih, 4 * kD, kX, 4 * kD, WcatT, kXH);                   // k in [0,2688)
    tc(W_hh, 4 * kD, kD, 4 * kD, WcatT + kX, kXH);              // k in [2688,3200)
    tc(W_fc,      kV, kD, kV, Wcat3T, kD);                      // rows 0..10000
    tc(W_dec_att, kA, kD, kA, Wcat3T + (long long)kV * kD, kD); // rows 10000..10512
    tc(W_fbeta,   kE, kD, kE, Wcat3T + (long long)(kV + kA) * kD, kD);
    bias_setup_kernel<<<(kN3 + 1024 + 2048 + 255) / 256, 256, 0, stream>>>(
        b_fc, b_dec_att, b_fbeta, b_init_h, b_init_c, b_ih, b_hh, bias3, bias_hc, gbias);

    if (use_encbf) {
        enc_cvt_kernel<<<(unsigned)(((long long)kB * kP * kE / 4 + 255) / 256), 256, 0, stream>>>(
            encoder_out, sort_ind, enc_bf);
    }
    mean_enc_kernel<<<(kB * kE) / 256, 256, 0, stream>>>(
        encoder_out, enc_bf, use_encbf, sort_ind, mean_enc);

    auto g2 = [](int M, int N) { return dim3((unsigned)((N + 127) / 128), (unsigned)(M / 64)); };

    // h0 | c0 in one GEMM (split epilogue)
    gemm2<<<g2(kB, 1024), 256, 0, stream>>>(mean_enc, kE, 0, WhcT, kE, bias_hc,
        xh + kX, kXH, 0, 512, c, kD, kBIG, nullptr, 0, nullptr, 0, 0,
        kB, 1024, kE, 0);

    // att1 (bf16) = enc_sorted @ W_enc_att + b_enc_att
    if (use_encbf) {
        gemm_big<<<dim3(kA / 128, kB * kP / 128), 256, 0, stream>>>(
            enc_bf, kE, WencT, kE, b_enc_att,
            att1_bf, kA, 1, nullptr, 0, kB * kP, kA, kE);
    } else {
        // A = unsorted f32 enc; att1 rows in ORIGINAL order; attn gathers via smap.
        gemm2<<<g2(kB * kP, kA), 256, 0, stream>>>(encoder_out, kE, 0, WencT, kE, b_enc_att,
            att1_bf, kA, 1, kBIG, nullptr, 0, kBIG, nullptr, 0, nullptr, 0, 0,
            kB * kP, kA, kE, 0);
    }

    // pre-loop: att2/gate for t=0 from h0
    gemm2<<<g2(kB, kA + kE), 256, 0, stream>>>(xh + kX, kXH, 0,
        Wcat3T + (long long)kV * kD, kD, bias3 + kV, att2, kA, 0,
        kA, gate, kE, kBIG, nullptr, 0, nullptr, 0, 0, kB, kA + kE, kD, 0);

    const int* smap = use_encbf ? nullptr : sort_ind;
    for (int t = 0; t < kT; t++) {
        attn_awe_kernel<<<dim3(2, kB), 512, 0, stream>>>(att1_bf, att2, w_full_att,
            b_full_att, encoder_out, enc_bf, use_encbf, sort_ind, gate, caps_i, t,
            emb_table, style, xh, o_alpha, declen, smap);
        // gates partials via split-K (KZ slices of K=3200)
        gemm2<<<dim3((4 * kD + 127) / 128, kB / 64, KZ), 256, 0, stream>>>(
            xh, kXH, 0, WcatT, kXH, nullptr,
            gpart, 4 * kD, 0, kBIG, nullptr, 0, kBIG, nullptr, 0, nullptr, 0, 0,
            kB, 4 * kD, kXH, (long long)kB * 4 * kD);
        lstm_cell_kernel<<<(kB * kD) / 256, 256, 0, stream>>>(gpart, gbias, xh, c, Hbuf, t);
        // att2_{t+1} | gate_{t+1}
        gemm2<<<g2(kB, kA + kE), 256, 0, stream>>>(xh + kX, kXH, 0,
            Wcat3T + (long long)kV * kD, kD, bias3 + kV, att2, kA, 0,
            kA, gate, kE, kBIG, nullptr, 0, nullptr, 0, 0, kB, kA + kE, kD, 0);
    }

    // Batched preds: [kT*kB, kV] = Hbuf @ W_fc + b_fc, masked by declen.
    gemm_big<<<dim3((kV + 127) / 128, kT * kB / 128), 256, 0, stream>>>(
        Hbuf, kD, Wcat3T, kD, bias3,
        o_pred, kV, 0, declen, 1, kT * kB, kV, kD);
}

// Round 4
// 2633.872 us; speedup vs baseline: 2.5418x; 1.0391x over previous
//
#include <hip/hip_runtime.h>
#include <math.h>

// Problem constants
constexpr int kB   = 128;
constexpr int kP   = 196;     // 14*14
constexpr int kPT  = 200;     // padded p (enc_T row length, pads zeroed)
constexpr int kE   = 2048;
constexpr int kA   = 512;
constexpr int kEMB = 512;
constexpr int kD   = 512;
constexpr int kV   = 10000;
constexpr int kLC  = 128;
constexpr int kTCAP= 26;
constexpr int kT   = 25;
constexpr int kX   = kEMB + kLC + kE;   // 2688
constexpr int kXH  = kX + kD;           // 3200 = [x | h]
constexpr int kN3  = kV + kA + kE;      // 12560 = [W_fc | W_dec_att | W_fbeta] cols
constexpr int kBIG = 1 << 30;
constexpr int KZ   = 5;                 // split-K factor for gates GEMM (3200/5 = 640)

typedef __attribute__((ext_vector_type(8))) short bf8;
typedef __attribute__((ext_vector_type(4))) float f4;

__device__ inline float b2f(ushort u) { return __uint_as_float(((unsigned)u) << 16); }
__device__ inline ushort f2b(float f) {  // round-to-nearest-even
    unsigned u = __float_as_uint(f);
    return (ushort)((u + 0x7fffu + ((u >> 16) & 1u)) >> 16);
}

// XOR-swizzled LDS short-index for GEMM tiles (row stride 32 shorts = 64B).
#define SWZ(r, k) ((((r) * 32) + (k)) ^ (((r) & 7) << 3))

// ---------------------------------------------------------------------------
// Sort + gathers (single block, 128 threads). Stable descending argsort.
// ---------------------------------------------------------------------------
__global__ __launch_bounds__(128) void sort_setup(
    const int* __restrict__ caplen, const int* __restrict__ caps_in,
    const int* __restrict__ lclass, const float* __restrict__ lc_table,
    int* __restrict__ sort_ind, int* __restrict__ declen, int* __restrict__ caps_i,
    float* __restrict__ style,
    float* __restrict__ out_caps, float* __restrict__ out_declen,
    float* __restrict__ out_sortind)
{
    __shared__ int lens[kB];
    __shared__ int sind[kB];
    int i = threadIdx.x;
    lens[i] = caplen[i];
    __syncthreads();
    int li = lens[i];
    int r = 0;
    for (int j = 0; j < kB; j++) {
        int lj = lens[j];
        if (lj > li || (lj == li && j < i)) r++;
    }
    sind[r] = i;
    sort_ind[r] = i;
    out_sortind[r] = (float)i;
    __syncthreads();
    int orig = sind[i];
    int dl = lens[orig] - 1;
    declen[i] = dl;
    out_declen[i] = (float)dl;
    for (int t = 0; t < kTCAP; t++) {
        int cv = caps_in[orig * kTCAP + t];
        caps_i[i * kTCAP + t] = cv;
        out_caps[i * kTCAP + t] = (float)cv;
    }
    int lcl = lclass[orig];
    for (int k = 0; k < kLC; k++) style[i * kLC + k] = lc_table[lcl * kLC + k];
}

// ---------------------------------------------------------------------------
// Transpose-convert: dst[n][k] (bf16, row stride ldd) = src[k][n] (f32, ldsrc)
// ---------------------------------------------------------------------------
__global__ __launch_bounds__(256) void tcvt_kernel(
    const float* __restrict__ src, int ldsrc, int K, int N,
    ushort* __restrict__ dst, long long ldd)
{
    __shared__ float tile[32][33];
    int k0 = blockIdx.y * 32, n0 = blockIdx.x * 32;
    int tx = threadIdx.x & 31, ty = threadIdx.x >> 5;   // 32 x 8
    #pragma unroll
    for (int j = 0; j < 4; j++) {
        int k = k0 + ty + j * 8, n = n0 + tx;
        tile[ty + j * 8][tx] = (k < K && n < N) ? src[(long long)k * ldsrc + n] : 0.f;
    }
    __syncthreads();
    #pragma unroll
    for (int j = 0; j < 4; j++) {
        int n = n0 + ty + j * 8, k = k0 + tx;
        if (n < N && k < K) dst[(long long)n * ldd + k] = f2b(tile[tx][ty + j * 8]);
    }
}

// bias3 = [b_fc | b_dec | b_fbeta]; bias_hc = [b_ih0 | b_ic0]; gbias = b_ih+b_hh
__global__ __launch_bounds__(256) void bias_setup_kernel(
    const float* __restrict__ b_fc, const float* __restrict__ b_dec,
    const float* __restrict__ b_fb, const float* __restrict__ b_ih0,
    const float* __restrict__ b_ic0, const float* __restrict__ b_ih,
    const float* __restrict__ b_hh,
    float* __restrict__ bias3, float* __restrict__ bias_hc, float* __restrict__ gbias)
{
    int idx = blockIdx.x * 256 + threadIdx.x;
    if (idx < kN3) {
        float v;
        if (idx < kV) v = b_fc[idx];
        else if (idx < kV + kA) v = b_dec[idx - kV];
        else v = b_fb[idx - kV - kA];
        bias3[idx] = v;
    } else if (idx < kN3 + 1024) {
        int i = idx - kN3;
        bias_hc[i] = (i < 512) ? b_ih0[i] : b_ic0[i - 512];
    } else if (idx < kN3 + 1024 + 2048) {
        int i = idx - kN3 - 1024;
        gbias[i] = b_ih[i] + b_hh[i];
    }
}

// enc (sorted) -> bf16: enc_bf[b][p][e] = bf16(enc[sort_ind[b]][p][e])
__global__ __launch_bounds__(256) void enc_cvt_kernel(
    const float* __restrict__ enc, const int* __restrict__ sort_ind,
    ushort* __restrict__ enc_bf)
{
    long long idx4 = (long long)blockIdx.x * 256 + threadIdx.x;
    if (idx4 >= (long long)kB * kP * kE / 4) return;
    int r = (int)(idx4 >> 9);          // dst row (b*196+p), 512 chunks/row
    int cc = ((int)idx4 & 511) * 4;
    int b = r / kP, p = r - b * kP;
    long long srow = (long long)sort_ind[b] * kP + p;
    float4 v = *(const float4*)(enc + srow * kE + cc);
    ushort4 o; o.x = f2b(v.x); o.y = f2b(v.y); o.z = f2b(v.z); o.w = f2b(v.w);
    *(ushort4*)(enc_bf + (long long)r * kE + cc) = o;
}

// ---------------------------------------------------------------------------
// enc_T[b][e][p] (p padded to 200, pads zero) from enc_bf[b][p][e].
// e-tile of 64: loads fully coalesced (one p-row of 64 shorts per wave),
// stores 200 contiguous shorts per (b,e) row. grid (kE/64, kB).
// ---------------------------------------------------------------------------
__global__ __launch_bounds__(256) void encT_kernel(
    const ushort* __restrict__ enc_bf, ushort* __restrict__ enc_T)
{
    __shared__ ushort tile[kPT][65];
    int b = blockIdx.y, e0 = blockIdx.x * 64;
    int tid = threadIdx.x;
    // zero pad rows 196..199
    tile[196 + (tid >> 6)][tid & 63] = 0;
    const ushort* src = enc_bf + (long long)b * kP * kE + e0;
    for (int idx = tid; idx < kP * 64; idx += 256) {
        int p = idx >> 6, j = idx & 63;
        tile[p][j] = src[(long long)p * kE + j];
    }
    __syncthreads();
    ushort* dst = enc_T + ((long long)b * kE + e0) * kPT;
    for (int j = 0; j < 64; j++) {
        if (tid < kPT) dst[(long long)j * kPT + tid] = tile[tid][j];
    }
}

// mean over p. Fast path: enc_T contiguous rows; fallbacks: strided.
__global__ __launch_bounds__(256) void mean_enc_kernel(
    const float* __restrict__ encf, const ushort* __restrict__ encb,
    const ushort* __restrict__ encT, int mode,  // 2=encT, 1=encb, 0=f32
    const int* __restrict__ sort_ind, float* __restrict__ me)
{
    int idx = blockIdx.x * 256 + threadIdx.x;   // b*2048 + e
    int b = idx >> 11, e = idx & 2047;
    float s = 0.f;
    if (mode == 2) {
        const ushort* base = encT + (long long)idx * kPT;
        #pragma unroll
        for (int i = 0; i < kPT / 8; i++) {
            uint4 u = *(const uint4*)(base + i * 8);
            const ushort* pu = (const ushort*)&u;
            #pragma unroll
            for (int j = 0; j < 8; j++) s += b2f(pu[j]);
        }
    } else if (mode == 1) {
        const ushort* base = encb + (long long)b * kP * kE + e;
        #pragma unroll 4
        for (int p = 0; p < kP; p++) s += b2f(base[(long long)p * kE]);
    } else {
        const float* base = encf + (long long)sort_ind[b] * kP * kE + e;
        #pragma unroll 4
        for (int p = 0; p < kP; p++) s += base[(long long)p * kE];
    }
    me[idx] = s * (1.0f / 196.0f);
}

// ---------------------------------------------------------------------------
// bf16 MFMA GEMM v4 (64x128 tile): C = A[M,K] @ Bt[N][K]^T + bias.
// ---------------------------------------------------------------------------
__global__ __launch_bounds__(256) void gemm2(
    const void* __restrict__ Am, int lda, int a_bf16,
    const ushort* __restrict__ Bt, int ldbt,
    const float* __restrict__ bias,
    void* __restrict__ out1, long long ldc1, int c1_bf16,
    int split1, float* __restrict__ out2, long long ldc2,
    int split2, float* __restrict__ out3, long long ldc3,
    const int* __restrict__ declen, int t, int pred_mode,
    int M, int N, int K, long long zstride)
{
    __shared__ short As[64 * 32];    // swizzled, 64B row stride
    __shared__ short Bs[128 * 32];
    int tid = threadIdx.x;
    int lane = tid & 63, w = tid >> 6, quad = lane >> 4, l16 = lane & 15;
    int m0 = blockIdx.y * 64, n0 = blockIdx.x * 128;

    f4 acc[8];
    #pragma unroll
    for (int i = 0; i < 8; i++) acc[i] = (f4){0.f, 0.f, 0.f, 0.f};

    int a_r = tid >> 2;
    int a_kc = (tid & 3) * 8;
    long long a_row = m0 + a_r;
    const float*  a_srcf = (const float*)Am  + a_row * (long long)lda + a_kc;
    const ushort* a_srcb = (const ushort*)Am + a_row * (long long)lda + a_kc;

    int b_r = tid >> 1;
    int b_kc = (tid & 1) * 16;
    bool bvalid = (n0 + b_r) < N;
    const ushort* b_src = Bt + (long long)(n0 + b_r) * ldbt + b_kc;

    int kpb = K / (int)gridDim.z;
    int kbeg = (int)blockIdx.z * kpb, kend = kbeg + kpb;

    float4 af0 = make_float4(0.f, 0.f, 0.f, 0.f), af1 = af0;
    uint4 au, bu0, bu1;
    au.x = au.y = au.z = au.w = 0u; bu0 = au; bu1 = au;

    if (a_bf16) au = *(const uint4*)(a_srcb + kbeg);
    else { af0 = *(const float4*)(a_srcf + kbeg); af1 = *(const float4*)(a_srcf + kbeg + 4); }
    if (bvalid) { bu0 = *(const uint4*)(b_src + kbeg); bu1 = *(const uint4*)(b_src + kbeg + 8); }

    for (int k0 = kbeg; k0 < kend; k0 += 32) {
        __syncthreads();
        if (a_bf16) {
            *(uint4*)&As[SWZ(a_r, a_kc)] = au;
        } else {
            uint4 pk; ushort* pp = (ushort*)&pk;
            pp[0] = f2b(af0.x); pp[1] = f2b(af0.y); pp[2] = f2b(af0.z); pp[3] = f2b(af0.w);
            pp[4] = f2b(af1.x); pp[5] = f2b(af1.y); pp[6] = f2b(af1.z); pp[7] = f2b(af1.w);
            *(uint4*)&As[SWZ(a_r, a_kc)] = pk;
        }
        *(uint4*)&Bs[SWZ(b_r, b_kc)]     = bu0;
        *(uint4*)&Bs[SWZ(b_r, b_kc + 8)] = bu1;
        int kn = k0 + 32;
        if (kn < kend) {
            if (a_bf16) au = *(const uint4*)(a_srcb + kn);
            else { af0 = *(const float4*)(a_srcf + kn); af1 = *(const float4*)(a_srcf + kn + 4); }
            if (bvalid) { bu0 = *(const uint4*)(b_src + kn); bu1 = *(const uint4*)(b_src + kn + 8); }
        }
        __syncthreads();
        bf8 a = *(const bf8*)&As[SWZ(w * 16 + l16, quad * 8)];
        #pragma unroll
        for (int nt = 0; nt < 8; nt++) {
            bf8 b = *(const bf8*)&Bs[SWZ(nt * 16 + l16, quad * 8)];
            acc[nt] = __builtin_amdgcn_mfma_f32_16x16x32_bf16(a, b, acc[nt], 0, 0, 0);
        }
    }

    long long zoff = (long long)blockIdx.z * zstride;
    #pragma unroll
    for (int nt = 0; nt < 8; nt++) {
        int cn = n0 + nt * 16 + l16;
        if (cn >= N) continue;
        float bv = bias ? bias[cn] : 0.f;
        #pragma unroll
        for (int reg = 0; reg < 4; reg++) {
            int rr = m0 + w * 16 + quad * 4 + reg;
            float v = acc[nt][reg] + bv;
            if (cn < split1) {
                long long idx;
                if (pred_mode) {
                    int bb = rr & 127, tt = rr >> 7;
                    if (tt >= declen[bb]) v = 0.f;
                    idx = ((long long)bb * kT + tt) * ldc1 + cn;
                } else {
                    if (declen && t >= declen[rr]) v = 0.f;
                    idx = (long long)rr * ldc1 + cn + zoff;
                }
                if (c1_bf16) ((ushort*)out1)[idx] = f2b(v);
                else         ((float*)out1)[idx] = v;
            } else if (cn < split2) {
                out2[(long long)rr * ldc2 + (cn - split1)] = v;
            } else {
                out3[(long long)rr * ldc3 + (cn - split2)] = v;
            }
        }
    }
}

// ---------------------------------------------------------------------------
// gemm_big: 128x128 tile, 4 waves in 2x2 grid, 4x4 fragments/wave (m97-style).
// ---------------------------------------------------------------------------
__global__ __launch_bounds__(256) void gemm_big(
    const ushort* __restrict__ A, int lda,
    const ushort* __restrict__ Bt, int ldbt,
    const float* __restrict__ bias,
    void* __restrict__ out1, long long ldc1, int c1_bf16,
    const int* __restrict__ declen, int pred_mode,
    int M, int N, int K)
{
    __shared__ short As[128 * 32];
    __shared__ short Bs[128 * 32];
    // XCD-chunked bijective swizzle (m204)
    unsigned nwg = gridDim.x * gridDim.y;
    unsigned lin = blockIdx.y * gridDim.x + blockIdx.x;
    unsigned q = nwg >> 3, rm = nwg & 7;
    unsigned xcd = lin & 7, loc = lin >> 3;
    unsigned swz = (xcd < rm ? xcd * (q + 1) : rm * (q + 1) + (xcd - rm) * q) + loc;
    int bx = (int)(swz % gridDim.x), by = (int)(swz / gridDim.x);
    int m0 = by * 128, n0 = bx * 128;

    int tid = threadIdx.x;
    int lane = tid & 63, w = tid >> 6, quad = lane >> 4, l16 = lane & 15;
    int wr = w >> 1, wc = w & 1;

    f4 acc[4][4];
    #pragma unroll
    for (int m = 0; m < 4; m++)
        #pragma unroll
        for (int n = 0; n < 4; n++) acc[m][n] = (f4){0.f, 0.f, 0.f, 0.f};

    bool wact = true;
    if (pred_mode) wact = declen[wr * 64] > (m0 >> 7);

    int s_r = tid >> 1, s_kc = (tid & 1) * 16;
    const ushort* a_src = A + (long long)(m0 + s_r) * lda + s_kc;
    bool bval = (n0 + s_r) < N;
    const ushort* b_src = Bt + (long long)(n0 + s_r) * ldbt + s_kc;

    uint4 au0, au1, bu0, bu1;
    au0.x = au0.y = au0.z = au0.w = 0u; au1 = au0; bu0 = au0; bu1 = au0;
    au0 = *(const uint4*)(a_src);
    au1 = *(const uint4*)(a_src + 8);
    if (bval) { bu0 = *(const uint4*)(b_src); bu1 = *(const uint4*)(b_src + 8); }

    for (int k0 = 0; k0 < K; k0 += 32) {
        __syncthreads();
        *(uint4*)&As[SWZ(s_r, s_kc)]     = au0;
        *(uint4*)&As[SWZ(s_r, s_kc + 8)] = au1;
        *(uint4*)&Bs[SWZ(s_r, s_kc)]     = bu0;
        *(uint4*)&Bs[SWZ(s_r, s_kc + 8)] = bu1;
        int kn = k0 + 32;
        if (kn < K) {
            au0 = *(const uint4*)(a_src + kn);
            au1 = *(const uint4*)(a_src + kn + 8);
            if (bval) { bu0 = *(const uint4*)(b_src + kn); bu1 = *(const uint4*)(b_src + kn + 8); }
        }
        __syncthreads();
        if (wact) {
            bf8 af[4], bfr[4];
            #pragma unroll
            for (int m = 0; m < 4; m++)
                af[m] = *(const bf8*)&As[SWZ(wr * 64 + m * 16 + l16, quad * 8)];
            #pragma unroll
            for (int n = 0; n < 4; n++)
                bfr[n] = *(const bf8*)&Bs[SWZ(wc * 64 + n * 16 + l16, quad * 8)];
            #pragma unroll
            for (int m = 0; m < 4; m++)
                #pragma unroll
                for (int n = 0; n < 4; n++)
                    acc[m][n] = __builtin_amdgcn_mfma_f32_16x16x32_bf16(af[m], bfr[n], acc[m][n], 0, 0, 0);
        }
    }

    #pragma unroll
    for (int n = 0; n < 4; n++) {
        int cn = n0 + wc * 64 + n * 16 + l16;
        if (cn >= N) continue;
        float bv = bias ? bias[cn] : 0.f;
        #pragma unroll
        for (int m = 0; m < 4; m++) {
            #pragma unroll
            for (int reg = 0; reg < 4; reg++) {
                int rr = m0 + wr * 64 + m * 16 + quad * 4 + reg;
                float v = acc[m][n][reg] + bv;
                long long idx;
                if (pred_mode) {
                    int bb = rr & 127, tt = rr >> 7;
                    if (tt >= declen[bb]) v = 0.f;
                    idx = ((long long)bb * kT + tt) * ldc1 + cn;
                } else {
                    idx = (long long)rr * ldc1 + cn;
                }
                if (c1_bf16) ((ushort*)out1)[idx] = f2b(v);
                else         ((float*)out1)[idx] = v;
            }
        }
    }
}

// ---------------------------------------------------------------------------
// Fused attention: energies + softmax + awe + build_x. grid (2, kB), 512 thr.
// awe fast path reads enc_T[b][e][200] (contiguous per-column streams).
// xh is bf16 end-to-end.
// ---------------------------------------------------------------------------
__global__ __launch_bounds__(512) void attn_awe_kernel(
    const ushort* __restrict__ att1, const float* __restrict__ att2,
    const float* __restrict__ w_full, const float* __restrict__ b_full,
    const float* __restrict__ encf, const ushort* __restrict__ encb,
    const ushort* __restrict__ encT, int mode,   // 2=encT, 1=encb, 0=f32
    const int* __restrict__ sort_ind, const float* __restrict__ gate,
    const int* __restrict__ caps_i, int t,
    const float* __restrict__ emb_table, const float* __restrict__ style,
    ushort* __restrict__ xh, float* __restrict__ alphas_out,
    const int* __restrict__ declen, const int* __restrict__ smap)
{
    int b = blockIdx.y;
    int half = blockIdx.x;
    int ob = smap ? smap[b] : b;
    __shared__ float al[kPT];
    __shared__ float red1[8], red2[8];
    int tid = threadIdx.x, wave = tid >> 6, lane = tid & 63;

    // --- energies: wave handles p = wave + 8*i, 4-deep load batching ---
    float a2r[8], wfr[8];
    {
        const float4* ap = (const float4*)(att2 + (long long)b * kA + lane * 8);
        *(float4*)&a2r[0] = ap[0]; *(float4*)&a2r[4] = ap[1];
        const float4* wp = (const float4*)(w_full + lane * 8);
        *(float4*)&wfr[0] = wp[0]; *(float4*)&wfr[4] = wp[1];
    }
    float bfull = b_full[0];
    const ushort* a1 = att1 + (long long)ob * kP * kA + lane * 8;
    for (int i0 = 0; i0 < 25; i0 += 4) {
        uint4 u[4]; int pv[4];
        #pragma unroll
        for (int j = 0; j < 4; j++) {
            int i = i0 + j, p = wave + 8 * i;
            pv[j] = (i < 25 && p < kP) ? p : -1;
            if (pv[j] >= 0) u[j] = *(const uint4*)(a1 + (long long)pv[j] * kA);
        }
        #pragma unroll
        for (int j = 0; j < 4; j++) {
            if (pv[j] < 0) continue;
            const unsigned* uw = (const unsigned*)&u[j];
            float s = 0.f;
            #pragma unroll
            for (int q = 0; q < 4; q++) {
                unsigned x = uw[q];
                float v0 = b2f((ushort)(x & 0xffffu)) + a2r[2 * q];
                float v1 = b2f((ushort)(x >> 16))     + a2r[2 * q + 1];
                s += fmaxf(v0, 0.f) * wfr[2 * q] + fmaxf(v1, 0.f) * wfr[2 * q + 1];
            }
            #pragma unroll
            for (int off = 32; off; off >>= 1) s += __shfl_down(s, off);
            if (lane == 0) al[pv[j]] = s + bfull;
        }
    }
    __syncthreads();

    // --- softmax over al[0..195] ---
    float e = (tid < kP) ? al[tid] : -1e30f;
    float wm = e;
    for (int off = 32; off; off >>= 1) wm = fmaxf(wm, __shfl_down(wm, off));
    if (lane == 0) red1[wave] = wm;
    __syncthreads();
    float gm = red1[0];
    #pragma unroll
    for (int i = 1; i < 8; i++) gm = fmaxf(gm, red1[i]);
    float ex = (tid < kP) ? expf(e - gm) : 0.f;
    float sw = ex;
    for (int off = 32; off; off >>= 1) sw += __shfl_down(sw, off);
    if (lane == 0) red2[wave] = sw;
    __syncthreads();
    float S = red2[0];
    #pragma unroll
    for (int i = 1; i < 8; i++) S += red2[i];
    float a = ex / S;
    __syncthreads();            // everyone done reading al as energies
    if (tid < kP) {
        al[tid] = a;
        if (half == 0)
            alphas_out[((long long)b * kT + t) * kP + tid] = (t < declen[b]) ? a : 0.f;
    } else if (tid < kPT) {
        al[tid] = 0.f;          // zero pad: enc_T pad cols multiply by 0
    }
    __syncthreads();

    // --- emb/style (half 1 only; independent of alpha), bf16 ---
    if (half == 1 && tid < 160) {
        int tok = caps_i[b * kTCAP + t];
        float4 v;
        if (tid < 128) v = *(const float4*)(emb_table + (long long)tok * kEMB + tid * 4);
        else           v = *(const float4*)(style + b * kLC + (tid - 128) * 4);
        ushort4 o; o.x = f2b(v.x); o.y = f2b(v.y); o.z = f2b(v.z); o.w = f2b(v.w);
        *(ushort4*)(xh + (long long)b * kXH + tid * 4) = o;
    }

    // --- awe: 512 threads x 2 cols in this half's 1024-col range ---
    int c0 = half * 1024 + tid * 2;
    float s0 = 0.f, s1 = 0.f;
    if (mode == 2) {
        const ushort* r0 = encT + ((long long)b * kE + c0) * kPT;
        const ushort* r1 = r0 + kPT;
        #pragma unroll 5
        for (int i = 0; i < kPT / 8; i++) {
            uint4 ua = *(const uint4*)(r0 + i * 8);
            uint4 ub = *(const uint4*)(r1 + i * 8);
            f4 alo = *(const f4*)&al[i * 8];
            f4 ahi = *(const f4*)&al[i * 8 + 4];
            const ushort* pa = (const ushort*)&ua;
            const ushort* pb = (const ushort*)&ub;
            s0 += b2f(pa[0]) * alo.x + b2f(pa[1]) * alo.y + b2f(pa[2]) * alo.z + b2f(pa[3]) * alo.w;
            s0 += b2f(pa[4]) * ahi.x + b2f(pa[5]) * ahi.y + b2f(pa[6]) * ahi.z + b2f(pa[7]) * ahi.w;
            s1 += b2f(pb[0]) * alo.x + b2f(pb[1]) * alo.y + b2f(pb[2]) * alo.z + b2f(pb[3]) * alo.w;
            s1 += b2f(pb[4]) * ahi.x + b2f(pb[5]) * ahi.y + b2f(pb[6]) * ahi.z + b2f(pb[7]) * ahi.w;
        }
    } else if (mode == 1) {
        const ushort* base = encb + (long long)b * kP * kE + c0;
        #pragma unroll 4
        for (int p = 0; p < kP; p++) {
            unsigned uu = *(const unsigned*)(base + (long long)p * kE);
            float ap = al[p];
            s0 += b2f((ushort)(uu & 0xffffu)) * ap;
            s1 += b2f((ushort)(uu >> 16))     * ap;
        }
    } else {
        const float* base = encf + (long long)sort_ind[b] * kP * kE + c0;
        #pragma unroll 4
        for (int p = 0; p < kP; p++) {
            float2 v = *(const float2*)(base + (long long)p * kE);
            float ap = al[p];
            s0 += v.x * ap; s1 += v.y * ap;
        }
    }
    float2 g = *(const float2*)(gate + (long long)b * kE + c0);
    float o0 = s0 / (1.f + expf(-g.x));
    float o1 = s1 / (1.f + expf(-g.y));
    unsigned pw = (unsigned)f2b(o0) | ((unsigned)f2b(o1) << 16);
    *(unsigned*)(xh + (long long)b * kXH + kEMB + kLC + c0) = pw;
}

// ---------------------------------------------------------------------------
// LSTM cell; reduces KZ split-K partials + gbias. h (bf16) -> xh[:,2688:3200]
// and Hbuf[t][b][:].
// ---------------------------------------------------------------------------
__global__ __launch_bounds__(256) void lstm_cell_kernel(
    const float* __restrict__ gpart, const float* __restrict__ gbias,
    ushort* __restrict__ xh, float* __restrict__ c,
    ushort* __restrict__ Hbuf, int t)
{
    int idx = blockIdx.x * 256 + threadIdx.x;   // b*512 + d
    int b = idx >> 9, d = idx & 511;
    float gi = gbias[d], gf = gbias[kD + d], gg = gbias[2 * kD + d], go = gbias[3 * kD + d];
    const float* g = gpart + (long long)b * 4 * kD + d;
    #pragma unroll
    for (int z = 0; z < KZ; z++) {
        const float* gz = g + (long long)z * kB * 4 * kD;
        gi += gz[0]; gf += gz[kD]; gg += gz[2 * kD]; go += gz[3 * kD];
    }
    float si = 1.f / (1.f + expf(-gi));
    float sf = 1.f / (1.f + expf(-gf));
    float so = 1.f / (1.f + expf(-go));
    float cn = sf * c[idx] + si * tanhf(gg);
    float hn = so * tanhf(cn);
    c[idx] = cn;
    ushort hb = f2b(hn);
    xh[(long long)b * kXH + kX + d] = hb;
    Hbuf[((long long)t * kB + b) * kD + d] = hb;
}

// ---------------------------------------------------------------------------
extern "C" void kernel_launch(void* const* d_in, const int* in_sizes, int n_in,
                              void* d_out, int out_size, void* d_ws, size_t ws_size,
                              hipStream_t stream)
{
    const float* encoder_out  = (const float*)d_in[0];
    const int*   enc_caps     = (const int*)  d_in[1];
    const int*   cap_lengths  = (const int*)  d_in[2];
    const int*   length_class = (const int*)  d_in[3];
    const float* W_enc_att = (const float*)d_in[4];
    const float* b_enc_att = (const float*)d_in[5];
    const float* W_dec_att = (const float*)d_in[6];
    const float* b_dec_att = (const float*)d_in[7];
    const float* w_full_att = (const float*)d_in[8];
    const float* b_full_att = (const float*)d_in[9];
    const float* W_init_h = (const float*)d_in[10];
    const float* b_init_h = (const float*)d_in[11];
    const float* W_init_c = (const float*)d_in[12];
    const float* b_init_c = (const float*)d_in[13];
    const float* W_fbeta  = (const float*)d_in[14];
    const float* b_fbeta  = (const float*)d_in[15];
    const float* emb_table = (const float*)d_in[16];
    const float* lc_table  = (const float*)d_in[17];
    const float* W_fc = (const float*)d_in[18];
    const float* b_fc = (const float*)d_in[19];
    const float* W_ih = (const float*)d_in[20];
    const float* b_ih = (const float*)d_in[21];
    const float* W_hh = (const float*)d_in[22];
    const float* b_hh = (const float*)d_in[23];

    // Output layout (flat float32, reference return order)
    float* out = (float*)d_out;
    float* o_pred    = out;                                  // B*T*V
    float* o_caps    = out + (long long)kB * kT * kV;
    float* o_declen  = o_caps + kB * kTCAP;
    float* o_alpha   = o_declen + kB;
    float* o_sortind = o_alpha + (long long)kB * kT * kP;

    // Workspace carve: f32 region, bf16 region, int region.
    float* w = (float*)d_ws;
    float* c        = w; w += kB * kD;
    float* att2     = w; w += kB * kA;
    float* gate     = w; w += kB * kE;
    float* mean_enc = w; w += kB * kE;
    float* gpart    = w; w += (long long)kB * 4 * kD * KZ;  // split-K partials
    float* style    = w; w += kB * kLC;
    float* bias3    = w; w += kN3;
    float* bias_hc  = w; w += 1024;
    float* gbias    = w; w += 2048;
    ushort* us = (ushort*)w;
    ushort* xh_bf    = us; us += (long long)kB * kXH;       // bf16 [emb|style|awe|h]
    ushort* att1_bf  = us; us += (long long)kB * kP * kA;   // 12.85M
    ushort* WencT    = us; us += (long long)kA * kE;        // [512][2048]
    ushort* WhcT     = us; us += (long long)1024 * kE;      // [1024][2048]
    ushort* WcatT    = us; us += (long long)(4 * kD) * kXH; // [2048][3200]
    ushort* Wcat3T   = us; us += (long long)kN3 * kD;       // [12560][512]
    ushort* Hbuf     = us; us += (long long)kT * kB * kD;   // [25*128][512] bf16
    int* iw = (int*)us;
    int* sort_ind = iw; iw += kB;
    int* declen   = iw; iw += kB;
    int* caps_i   = iw; iw += kB * kTCAP;
    ushort* enc_bf = (ushort*)(iw + kB);                    // 102.8 MB (optional)
    ushort* enc_T  = enc_bf + (long long)kB * kP * kE;      // 104.9 MB (optional)

    // Decide enc paths by workspace headroom (ws_size is call-invariant).
    size_t need_encbf = ((char*)(enc_bf + (long long)kB * kP * kE)) - (char*)d_ws;
    size_t need_encT  = ((char*)(enc_T  + (long long)kB * kE * kPT)) - (char*)d_ws;
    int use_encbf = (ws_size >= need_encbf) ? 1 : 0;
    int use_encT  = (ws_size >= need_encT) ? 1 : 0;
    int mode = use_encT ? 2 : (use_encbf ? 1 : 0);

    sort_setup<<<1, 128, 0, stream>>>(cap_lengths, enc_caps, length_class, lc_table,
        sort_ind, declen, caps_i, style, o_caps, o_declen, o_sortind);

    // One-time weight prep: transpose-convert all B matrices to [N][K] bf16.
    auto tc = [&](const float* s, int ldsrc, int Kr, int Nc, ushort* d, long long ldd) {
        tcvt_kernel<<<dim3((Nc + 31) / 32, (Kr + 31) / 32), 256, 0, stream>>>(
            s, ldsrc, Kr, Nc, d, ldd);
    };
    tc(W_enc_att, kA, kE, kA, WencT, kE);                       // [512][2048]
    tc(W_init_h,  kD, kE, kD, WhcT, kE);                        // rows 0..512
    tc(W_init_c,  kD, kE, kD, WhcT + (long long)kD * kE, kE);   // rows 512..1024
    tc(W_ih, 4 * kD, kX, 4 * kD, WcatT, kXH);                   // k in [0,2688)
    tc(W_hh, 4 * kD, kD, 4 * kD, WcatT + kX, kXH);              // k in [2688,3200)
    tc(W_fc,      kV, kD, kV, Wcat3T, kD);                      // rows 0..10000
    tc(W_dec_att, kA, kD, kA, Wcat3T + (long long)kV * kD, kD); // rows 10000..10512
    tc(W_fbeta,   kE, kD, kE, Wcat3T + (long long)(kV + kA) * kD, kD);
    bias_setup_kernel<<<(kN3 + 1024 + 2048 + 255) / 256, 256, 0, stream>>>(
        b_fc, b_dec_att, b_fbeta, b_init_h, b_init_c, b_ih, b_hh, bias3, bias_hc, gbias);

    if (use_encbf) {
        enc_cvt_kernel<<<(unsigned)(((long long)kB * kP * kE / 4 + 255) / 256), 256, 0, stream>>>(
            encoder_out, sort_ind, enc_bf);
    }
    if (use_encT) {
        encT_kernel<<<dim3(kE / 64, kB), 256, 0, stream>>>(enc_bf, enc_T);
    }
    mean_enc_kernel<<<(kB * kE) / 256, 256, 0, stream>>>(
        encoder_out, enc_bf, enc_T, mode, sort_ind, mean_enc);

    auto g2 = [](int M, int N) { return dim3((unsigned)((N + 127) / 128), (unsigned)(M / 64)); };

    // h0 (bf16 -> xh_bf) | c0 (f32) in one GEMM (split epilogue)
    gemm2<<<g2(kB, 1024), 256, 0, stream>>>(mean_enc, kE, 0, WhcT, kE, bias_hc,
        xh_bf + kX, kXH, 1, 512, c, kD, kBIG, nullptr, 0, nullptr, 0, 0,
        kB, 1024, kE, 0);

    // att1 (bf16) = enc_sorted @ W_enc_att + b_enc_att
    if (use_encbf) {
        gemm_big<<<dim3(kA / 128, kB * kP / 128), 256, 0, stream>>>(
            enc_bf, kE, WencT, kE, b_enc_att,
            att1_bf, kA, 1, nullptr, 0, kB * kP, kA, kE);
    } else {
        gemm2<<<g2(kB * kP, kA), 256, 0, stream>>>(encoder_out, kE, 0, WencT, kE, b_enc_att,
            att1_bf, kA, 1, kBIG, nullptr, 0, kBIG, nullptr, 0, nullptr, 0, 0,
            kB * kP, kA, kE, 0);
    }

    // pre-loop: att2/gate for t=0 from h0 (A = bf16 h in xh_bf)
    gemm2<<<g2(kB, kA + kE), 256, 0, stream>>>(xh_bf + kX, kXH, 1,
        Wcat3T + (long long)kV * kD, kD, bias3 + kV, att2, kA, 0,
        kA, gate, kE, kBIG, nullptr, 0, nullptr, 0, 0, kB, kA + kE, kD, 0);

    const int* smap = use_encbf ? nullptr : sort_ind;
    for (int t = 0; t < kT; t++) {
        attn_awe_kernel<<<dim3(2, kB), 512, 0, stream>>>(att1_bf, att2, w_full_att,
            b_full_att, encoder_out, enc_bf, enc_T, mode, sort_ind, gate, caps_i, t,
            emb_table, style, xh_bf, o_alpha, declen, smap);
        // gates partials via split-K (KZ slices of K=3200), A = bf16 xh
        gemm2<<<dim3((4 * kD + 127) / 128, kB / 64, KZ), 256, 0, stream>>>(
            xh_bf, kXH, 1, WcatT, kXH, nullptr,
            gpart, 4 * kD, 0, kBIG, nullptr, 0, kBIG, nullptr, 0, nullptr, 0, 0,
            kB, 4 * kD, kXH, (long long)kB * 4 * kD);
        lstm_cell_kernel<<<(kB * kD) / 256, 256, 0, stream>>>(gpart, gbias, xh_bf, c, Hbuf, t);
        // att2_{t+1} | gate_{t+1}  (A = bf16 h)
        gemm2<<<g2(kB, kA + kE), 256, 0, stream>>>(xh_bf + kX, kXH, 1,
            Wcat3T + (long long)kV * kD, kD, bias3 + kV, att2, kA, 0,
            kA, gate, kE, kBIG, nullptr, 0, nullptr, 0, 0, kB, kA + kE, kD, 0);
    }

    // Batched preds: [kT*kB, kV] = Hbuf @ W_fc + b_fc, masked by declen.
    gemm_big<<<dim3((kV + 127) / 128, kT * kB / 128), 256, 0, stream>>>(
        Hbuf, kD, Wcat3T, kD, bias3,
        o_pred, kV, 0, declen, 1, kT * kB, kV, kD);
}

// Round 5
// 2442.636 us; speedup vs baseline: 2.7408x; 1.0783x over previous
//
#include <hip/hip_runtime.h>
#include <math.h>

// Problem constants
constexpr int kB   = 128;
constexpr int kP   = 196;     // 14*14
constexpr int kPT  = 200;     // padded p (enc_T row length, pads zeroed)
constexpr int kE   = 2048;
constexpr int kA   = 512;
constexpr int kEMB = 512;
constexpr int kD   = 512;
constexpr int kV   = 10000;
constexpr int kLC  = 128;
constexpr int kTCAP= 26;
constexpr int kT   = 25;
constexpr int kX   = kEMB + kLC + kE;   // 2688
constexpr int kXH  = kX + kD;           // 3200 = [x | h]
constexpr int kN3  = kV + kA + kE;      // 12560
constexpr int kBIG = 1 << 30;
constexpr int KZ   = 5;                 // split-K factor for gates GEMM

typedef __attribute__((ext_vector_type(8))) short bf8;
typedef __attribute__((ext_vector_type(4))) float f4;

__device__ inline float b2f(ushort u) { return __uint_as_float(((unsigned)u) << 16); }
__device__ inline ushort f2b(float f) {  // round-to-nearest-even
    unsigned u = __float_as_uint(f);
    return (ushort)((u + 0x7fffu + ((u >> 16) & 1u)) >> 16);
}

// XOR-swizzled LDS short-index for GEMM tiles (row stride 32 shorts = 64B).
#define SWZ(r, k) ((((r) * 32) + (k)) ^ (((r) & 7) << 3))

// ---------------------------------------------------------------------------
// Sort + gathers (single block, 128 threads). Stable descending argsort.
// ---------------------------------------------------------------------------
__global__ __launch_bounds__(128) void sort_setup(
    const int* __restrict__ caplen, const int* __restrict__ caps_in,
    const int* __restrict__ lclass, const float* __restrict__ lc_table,
    int* __restrict__ sort_ind, int* __restrict__ declen, int* __restrict__ caps_i,
    float* __restrict__ style,
    float* __restrict__ out_caps, float* __restrict__ out_declen,
    float* __restrict__ out_sortind)
{
    __shared__ int lens[kB];
    __shared__ int sind[kB];
    int i = threadIdx.x;
    lens[i] = caplen[i];
    __syncthreads();
    int li = lens[i];
    int r = 0;
    for (int j = 0; j < kB; j++) {
        int lj = lens[j];
        if (lj > li || (lj == li && j < i)) r++;
    }
    sind[r] = i;
    sort_ind[r] = i;
    out_sortind[r] = (float)i;
    __syncthreads();
    int orig = sind[i];
    int dl = lens[orig] - 1;
    declen[i] = dl;
    out_declen[i] = (float)dl;
    for (int t = 0; t < kTCAP; t++) {
        int cv = caps_in[orig * kTCAP + t];
        caps_i[i * kTCAP + t] = cv;
        out_caps[i * kTCAP + t] = (float)cv;
    }
    int lcl = lclass[orig];
    for (int k = 0; k < kLC; k++) style[i * kLC + k] = lc_table[lcl * kLC + k];
}

// ---------------------------------------------------------------------------
// Transpose-convert: dst[n][k] (bf16, row stride ldd) = src[k][n] (f32, ldsrc)
// ---------------------------------------------------------------------------
__global__ __launch_bounds__(256) void tcvt_kernel(
    const float* __restrict__ src, int ldsrc, int K, int N,
    ushort* __restrict__ dst, long long ldd)
{
    __shared__ float tile[32][33];
    int k0 = blockIdx.y * 32, n0 = blockIdx.x * 32;
    int tx = threadIdx.x & 31, ty = threadIdx.x >> 5;   // 32 x 8
    #pragma unroll
    for (int j = 0; j < 4; j++) {
        int k = k0 + ty + j * 8, n = n0 + tx;
        tile[ty + j * 8][tx] = (k < K && n < N) ? src[(long long)k * ldsrc + n] : 0.f;
    }
    __syncthreads();
    #pragma unroll
    for (int j = 0; j < 4; j++) {
        int n = n0 + ty + j * 8, k = k0 + tx;
        if (n < N && k < K) dst[(long long)n * ldd + k] = f2b(tile[tx][ty + j * 8]);
    }
}

// bias3 = [b_fc | b_dec | b_fbeta]; bias_hc = [b_ih0 | b_ic0]; gbias = b_ih+b_hh
__global__ __launch_bounds__(256) void bias_setup_kernel(
    const float* __restrict__ b_fc, const float* __restrict__ b_dec,
    const float* __restrict__ b_fb, const float* __restrict__ b_ih0,
    const float* __restrict__ b_ic0, const float* __restrict__ b_ih,
    const float* __restrict__ b_hh,
    float* __restrict__ bias3, float* __restrict__ bias_hc, float* __restrict__ gbias)
{
    int idx = blockIdx.x * 256 + threadIdx.x;
    if (idx < kN3) {
        float v;
        if (idx < kV) v = b_fc[idx];
        else if (idx < kV + kA) v = b_dec[idx - kV];
        else v = b_fb[idx - kV - kA];
        bias3[idx] = v;
    } else if (idx < kN3 + 1024) {
        int i = idx - kN3;
        bias_hc[i] = (i < 512) ? b_ih0[i] : b_ic0[i - 512];
    } else if (idx < kN3 + 1024 + 2048) {
        int i = idx - kN3 - 1024;
        gbias[i] = b_ih[i] + b_hh[i];
    }
}

// enc (sorted) -> bf16: enc_bf[b][p][e] = bf16(enc[sort_ind[b]][p][e])
__global__ __launch_bounds__(256) void enc_cvt_kernel(
    const float* __restrict__ enc, const int* __restrict__ sort_ind,
    ushort* __restrict__ enc_bf)
{
    long long idx4 = (long long)blockIdx.x * 256 + threadIdx.x;
    if (idx4 >= (long long)kB * kP * kE / 4) return;
    int r = (int)(idx4 >> 9);          // dst row (b*196+p), 512 chunks/row
    int cc = ((int)idx4 & 511) * 4;
    int b = r / kP, p = r - b * kP;
    long long srow = (long long)sort_ind[b] * kP + p;
    float4 v = *(const float4*)(enc + srow * kE + cc);
    ushort4 o; o.x = f2b(v.x); o.y = f2b(v.y); o.z = f2b(v.z); o.w = f2b(v.w);
    *(ushort4*)(enc_bf + (long long)r * kE + cc) = o;
}

// ---------------------------------------------------------------------------
// enc_T[b][e][p] (p padded to 200, pads zero) from enc_bf[b][p][e].
// ---------------------------------------------------------------------------
__global__ __launch_bounds__(256) void encT_kernel(
    const ushort* __restrict__ enc_bf, ushort* __restrict__ enc_T)
{
    __shared__ ushort tile[kPT][65];
    int b = blockIdx.y, e0 = blockIdx.x * 64;
    int tid = threadIdx.x;
    tile[196 + (tid >> 6)][tid & 63] = 0;
    const ushort* src = enc_bf + (long long)b * kP * kE + e0;
    for (int idx = tid; idx < kP * 64; idx += 256) {
        int p = idx >> 6, j = idx & 63;
        tile[p][j] = src[(long long)p * kE + j];
    }
    __syncthreads();
    ushort* dst = enc_T + ((long long)b * kE + e0) * kPT;
    for (int j = 0; j < 64; j++) {
        if (tid < kPT) dst[(long long)j * kPT + tid] = tile[tid][j];
    }
}

// mean over p. Fast path: enc_T contiguous rows; fallbacks: strided.
__global__ __launch_bounds__(256) void mean_enc_kernel(
    const float* __restrict__ encf, const ushort* __restrict__ encb,
    const ushort* __restrict__ encT, int mode,  // 2=encT, 1=encb, 0=f32
    const int* __restrict__ sort_ind, float* __restrict__ me)
{
    int idx = blockIdx.x * 256 + threadIdx.x;   // b*2048 + e
    int b = idx >> 11, e = idx & 2047;
    float s = 0.f;
    if (mode == 2) {
        const ushort* base = encT + (long long)idx * kPT;
        #pragma unroll
        for (int i = 0; i < kPT / 8; i++) {
            uint4 u = *(const uint4*)(base + i * 8);
            const ushort* pu = (const ushort*)&u;
            #pragma unroll
            for (int j = 0; j < 8; j++) s += b2f(pu[j]);
        }
    } else if (mode == 1) {
        const ushort* base = encb + (long long)b * kP * kE + e;
        #pragma unroll 4
        for (int p = 0; p < kP; p++) s += b2f(base[(long long)p * kE]);
    } else {
        const float* base = encf + (long long)sort_ind[b] * kP * kE + e;
        #pragma unroll 4
        for (int p = 0; p < kP; p++) s += base[(long long)p * kE];
    }
    me[idx] = s * (1.0f / 196.0f);
}

// ---------------------------------------------------------------------------
// bf16 MFMA GEMM v4 (64x128 tile): C = A[M,K] @ Bt[N][K]^T + bias.
// ---------------------------------------------------------------------------
__global__ __launch_bounds__(256) void gemm2(
    const void* __restrict__ Am, int lda, int a_bf16,
    const ushort* __restrict__ Bt, int ldbt,
    const float* __restrict__ bias,
    void* __restrict__ out1, long long ldc1, int c1_bf16,
    int split1, float* __restrict__ out2, long long ldc2,
    int split2, float* __restrict__ out3, long long ldc3,
    const int* __restrict__ declen, int t, int pred_mode,
    int M, int N, int K, long long zstride)
{
    __shared__ short As[64 * 32];    // swizzled, 64B row stride
    __shared__ short Bs[128 * 32];
    int tid = threadIdx.x;
    int lane = tid & 63, w = tid >> 6, quad = lane >> 4, l16 = lane & 15;
    int m0 = blockIdx.y * 64, n0 = blockIdx.x * 128;

    f4 acc[8];
    #pragma unroll
    for (int i = 0; i < 8; i++) acc[i] = (f4){0.f, 0.f, 0.f, 0.f};

    int a_r = tid >> 2;
    int a_kc = (tid & 3) * 8;
    long long a_row = m0 + a_r;
    const float*  a_srcf = (const float*)Am  + a_row * (long long)lda + a_kc;
    const ushort* a_srcb = (const ushort*)Am + a_row * (long long)lda + a_kc;

    int b_r = tid >> 1;
    int b_kc = (tid & 1) * 16;
    bool bvalid = (n0 + b_r) < N;
    const ushort* b_src = Bt + (long long)(n0 + b_r) * ldbt + b_kc;

    int kpb = K / (int)gridDim.z;
    int kbeg = (int)blockIdx.z * kpb, kend = kbeg + kpb;

    float4 af0 = make_float4(0.f, 0.f, 0.f, 0.f), af1 = af0;
    uint4 au, bu0, bu1;
    au.x = au.y = au.z = au.w = 0u; bu0 = au; bu1 = au;

    if (a_bf16) au = *(const uint4*)(a_srcb + kbeg);
    else { af0 = *(const float4*)(a_srcf + kbeg); af1 = *(const float4*)(a_srcf + kbeg + 4); }
    if (bvalid) { bu0 = *(const uint4*)(b_src + kbeg); bu1 = *(const uint4*)(b_src + kbeg + 8); }

    for (int k0 = kbeg; k0 < kend; k0 += 32) {
        __syncthreads();
        if (a_bf16) {
            *(uint4*)&As[SWZ(a_r, a_kc)] = au;
        } else {
            uint4 pk; ushort* pp = (ushort*)&pk;
            pp[0] = f2b(af0.x); pp[1] = f2b(af0.y); pp[2] = f2b(af0.z); pp[3] = f2b(af0.w);
            pp[4] = f2b(af1.x); pp[5] = f2b(af1.y); pp[6] = f2b(af1.z); pp[7] = f2b(af1.w);
            *(uint4*)&As[SWZ(a_r, a_kc)] = pk;
        }
        *(uint4*)&Bs[SWZ(b_r, b_kc)]     = bu0;
        *(uint4*)&Bs[SWZ(b_r, b_kc + 8)] = bu1;
        int kn = k0 + 32;
        if (kn < kend) {
            if (a_bf16) au = *(const uint4*)(a_srcb + kn);
            else { af0 = *(const float4*)(a_srcf + kn); af1 = *(const float4*)(a_srcf + kn + 4); }
            if (bvalid) { bu0 = *(const uint4*)(b_src + kn); bu1 = *(const uint4*)(b_src + kn + 8); }
        }
        __syncthreads();
        bf8 a = *(const bf8*)&As[SWZ(w * 16 + l16, quad * 8)];
        #pragma unroll
        for (int nt = 0; nt < 8; nt++) {
            bf8 b = *(const bf8*)&Bs[SWZ(nt * 16 + l16, quad * 8)];
            acc[nt] = __builtin_amdgcn_mfma_f32_16x16x32_bf16(a, b, acc[nt], 0, 0, 0);
        }
    }

    long long zoff = (long long)blockIdx.z * zstride;
    #pragma unroll
    for (int nt = 0; nt < 8; nt++) {
        int cn = n0 + nt * 16 + l16;
        if (cn >= N) continue;
        float bv = bias ? bias[cn] : 0.f;
        #pragma unroll
        for (int reg = 0; reg < 4; reg++) {
            int rr = m0 + w * 16 + quad * 4 + reg;
            float v = acc[nt][reg] + bv;
            if (cn < split1) {
                long long idx;
                if (pred_mode) {
                    int bb = rr & 127, tt = rr >> 7;
                    if (tt >= declen[bb]) v = 0.f;
                    idx = ((long long)bb * kT + tt) * ldc1 + cn;
                } else {
                    if (declen && t >= declen[rr]) v = 0.f;
                    idx = (long long)rr * ldc1 + cn + zoff;
                }
                if (c1_bf16) ((ushort*)out1)[idx] = f2b(v);
                else         ((float*)out1)[idx] = v;
            } else if (cn < split2) {
                out2[(long long)rr * ldc2 + (cn - split1)] = v;
            } else {
                out3[(long long)rr * ldc3 + (cn - split2)] = v;
            }
        }
    }
}

// ---------------------------------------------------------------------------
// gemm_big: 128x128 tile, 4 waves in 2x2 grid, 4x4 fragments/wave.
// f32 output path uses LDS-staged epilogue: 32-col chunks assembled in Cs,
// then 128B-contiguous row writes (full-L2-line where aligned; kills the
// write-allocate RMW seen as FETCH_SIZE ~= output size).
// ---------------------------------------------------------------------------
__global__ __launch_bounds__(256) void gemm_big(
    const ushort* __restrict__ A, int lda,
    const ushort* __restrict__ Bt, int ldbt,
    const float* __restrict__ bias,
    void* __restrict__ out1, long long ldc1, int c1_bf16,
    const int* __restrict__ declen, int pred_mode,
    int M, int N, int K)
{
    __shared__ short As[128 * 32];
    __shared__ short Bs[128 * 32];
    __shared__ float Cs[128][33];
    // XCD-chunked bijective swizzle (m204)
    unsigned nwg = gridDim.x * gridDim.y;
    unsigned lin = blockIdx.y * gridDim.x + blockIdx.x;
    unsigned q = nwg >> 3, rm = nwg & 7;
    unsigned xcd = lin & 7, loc = lin >> 3;
    unsigned swz = (xcd < rm ? xcd * (q + 1) : rm * (q + 1) + (xcd - rm) * q) + loc;
    int bx = (int)(swz % gridDim.x), by = (int)(swz / gridDim.x);
    int m0 = by * 128, n0 = bx * 128;

    int tid = threadIdx.x;
    int lane = tid & 63, w = tid >> 6, quad = lane >> 4, l16 = lane & 15;
    int wr = w >> 1, wc = w & 1;

    f4 acc[4][4];
    #pragma unroll
    for (int m = 0; m < 4; m++)
        #pragma unroll
        for (int n = 0; n < 4; n++) acc[m][n] = (f4){0.f, 0.f, 0.f, 0.f};

    bool wact = true;
    if (pred_mode) wact = declen[wr * 64] > (m0 >> 7);

    int s_r = tid >> 1, s_kc = (tid & 1) * 16;
    const ushort* a_src = A + (long long)(m0 + s_r) * lda + s_kc;
    bool bval = (n0 + s_r) < N;
    const ushort* b_src = Bt + (long long)(n0 + s_r) * ldbt + s_kc;

    uint4 au0, au1, bu0, bu1;
    au0.x = au0.y = au0.z = au0.w = 0u; au1 = au0; bu0 = au0; bu1 = au0;
    au0 = *(const uint4*)(a_src);
    au1 = *(const uint4*)(a_src + 8);
    if (bval) { bu0 = *(const uint4*)(b_src); bu1 = *(const uint4*)(b_src + 8); }

    for (int k0 = 0; k0 < K; k0 += 32) {
        __syncthreads();
        *(uint4*)&As[SWZ(s_r, s_kc)]     = au0;
        *(uint4*)&As[SWZ(s_r, s_kc + 8)] = au1;
        *(uint4*)&Bs[SWZ(s_r, s_kc)]     = bu0;
        *(uint4*)&Bs[SWZ(s_r, s_kc + 8)] = bu1;
        int kn = k0 + 32;
        if (kn < K) {
            au0 = *(const uint4*)(a_src + kn);
            au1 = *(const uint4*)(a_src + kn + 8);
            if (bval) { bu0 = *(const uint4*)(b_src + kn); bu1 = *(const uint4*)(b_src + kn + 8); }
        }
        __syncthreads();
        if (wact) {
            bf8 af[4], bfr[4];
            #pragma unroll
            for (int m = 0; m < 4; m++)
                af[m] = *(const bf8*)&As[SWZ(wr * 64 + m * 16 + l16, quad * 8)];
            #pragma unroll
            for (int n = 0; n < 4; n++)
                bfr[n] = *(const bf8*)&Bs[SWZ(wc * 64 + n * 16 + l16, quad * 8)];
            #pragma unroll
            for (int m = 0; m < 4; m++)
                #pragma unroll
                for (int n = 0; n < 4; n++)
                    acc[m][n] = __builtin_amdgcn_mfma_f32_16x16x32_bf16(af[m], bfr[n], acc[m][n], 0, 0, 0);
        }
    }

    if (c1_bf16) {
        #pragma unroll
        for (int n = 0; n < 4; n++) {
            int cn = n0 + wc * 64 + n * 16 + l16;
            if (cn >= N) continue;
            float bv = bias ? bias[cn] : 0.f;
            #pragma unroll
            for (int m = 0; m < 4; m++) {
                #pragma unroll
                for (int reg = 0; reg < 4; reg++) {
                    int rr = m0 + wr * 64 + m * 16 + quad * 4 + reg;
                    float v = acc[m][n][reg] + bv;
                    long long idx;
                    if (pred_mode) {
                        int bb = rr & 127, tt = rr >> 7;
                        if (tt >= declen[bb]) v = 0.f;
                        idx = ((long long)bb * kT + tt) * ldc1 + cn;
                    } else {
                        idx = (long long)rr * ldc1 + cn;
                    }
                    ((ushort*)out1)[idx] = f2b(v);
                }
            }
        }
    } else {
        // LDS-staged f32 epilogue: 4 chunks of 32 cols
        #pragma unroll
        for (int ch = 0; ch < 4; ch++) {
            __syncthreads();
            if (wc == (ch >> 1)) {
                #pragma unroll
                for (int nn = 0; nn < 2; nn++) {
                    int n = (ch & 1) * 2 + nn;
                    int cn = n0 + wc * 64 + n * 16 + l16;
                    float bv = bias ? bias[cn] : 0.f;
                    #pragma unroll
                    for (int m = 0; m < 4; m++) {
                        int r = wr * 64 + m * 16 + quad * 4;
                        #pragma unroll
                        for (int reg = 0; reg < 4; reg++)
                            Cs[r + reg][nn * 16 + l16] = acc[m][n][reg] + bv;
                    }
                }
            }
            __syncthreads();
            int ccol0 = n0 + (ch >> 1) * 64 + (ch & 1) * 32;
            int tr = tid >> 3;            // 32 rows per round
            int tc = (tid & 7) * 4;       // 4 cols per thread
            #pragma unroll
            for (int rr4 = 0; rr4 < 4; rr4++) {
                int r = rr4 * 32 + tr;
                int grow = m0 + r;
                int cn = ccol0 + tc;
                if (cn >= N) continue;
                float4 v = *(const float4*)&Cs[r][tc];
                long long idx;
                if (pred_mode) {
                    int bb = grow & 127, tt = grow >> 7;
                    if (tt >= declen[bb]) v = make_float4(0.f, 0.f, 0.f, 0.f);
                    idx = ((long long)bb * kT + tt) * ldc1 + cn;
                } else {
                    idx = (long long)grow * ldc1 + cn;
                }
                *(float4*)((float*)out1 + idx) = v;
            }
        }
    }
}

// ---------------------------------------------------------------------------
// Energy kernel: es[b][p] = relu(att1[p,:] + att2[b,:]) . w_full + b_full.
// grid (2, kB) x 512 thr; block half handles p in [half*98, half*98+98).
// ---------------------------------------------------------------------------
__global__ __launch_bounds__(512) void energy_kernel(
    const ushort* __restrict__ att1, const float* __restrict__ att2,
    const float* __restrict__ w_full, const float* __restrict__ b_full,
    float* __restrict__ es, const int* __restrict__ smap)
{
    int b = blockIdx.y, half = blockIdx.x;
    int ob = smap ? smap[b] : b;
    int tid = threadIdx.x, wave = tid >> 6, lane = tid & 63;
    float a2r[8], wfr[8];
    {
        const float4* ap = (const float4*)(att2 + (long long)b * kA + lane * 8);
        *(float4*)&a2r[0] = ap[0]; *(float4*)&a2r[4] = ap[1];
        const float4* wp = (const float4*)(w_full + lane * 8);
        *(float4*)&wfr[0] = wp[0]; *(float4*)&wfr[4] = wp[1];
    }
    float bfull = b_full[0];
    int p0 = half * 98;
    const ushort* a1 = att1 + ((long long)ob * kP + p0) * kA + lane * 8;
    for (int i0 = 0; i0 < 13; i0 += 4) {
        uint4 u[4]; int pl[4];
        #pragma unroll
        for (int j = 0; j < 4; j++) {
            int i = i0 + j, p = wave + 8 * i;
            pl[j] = (i < 13 && p < 98) ? p : -1;
            if (pl[j] >= 0) u[j] = *(const uint4*)(a1 + (long long)pl[j] * kA);
        }
        #pragma unroll
        for (int j = 0; j < 4; j++) {
            if (pl[j] < 0) continue;
            const unsigned* uw = (const unsigned*)&u[j];
            float s = 0.f;
            #pragma unroll
            for (int qq = 0; qq < 4; qq++) {
                unsigned x = uw[qq];
                float v0 = b2f((ushort)(x & 0xffffu)) + a2r[2 * qq];
                float v1 = b2f((ushort)(x >> 16))     + a2r[2 * qq + 1];
                s += fmaxf(v0, 0.f) * wfr[2 * qq] + fmaxf(v1, 0.f) * wfr[2 * qq + 1];
            }
            #pragma unroll
            for (int off = 32; off; off >>= 1) s += __shfl_down(s, off);
            if (lane == 0) es[b * kP + p0 + pl[j]] = s + bfull;
        }
    }
}

// ---------------------------------------------------------------------------
// awe kernel: grid (9, kB) x 256 thr. Every block redoes the cheap softmax
// from es (196 floats). x<8: 256 awe cols each (1 col/thread, contiguous
// enc_T row stream). x==8: alphas_out + emb/style.
// ---------------------------------------------------------------------------
__global__ __launch_bounds__(256) void awe_kernel(
    const float* __restrict__ es,
    const float* __restrict__ encf, const ushort* __restrict__ encb,
    const ushort* __restrict__ encT, int mode,   // 2=encT, 1=encb, 0=f32
    const int* __restrict__ sort_ind, const float* __restrict__ gate,
    const int* __restrict__ caps_i, int t,
    const float* __restrict__ emb_table, const float* __restrict__ style,
    ushort* __restrict__ xh, float* __restrict__ alphas_out,
    const int* __restrict__ declen)
{
    int b = blockIdx.y, x = blockIdx.x;
    __shared__ float al[kPT];
    __shared__ float red1[4], red2[4];
    int tid = threadIdx.x, wave = tid >> 6, lane = tid & 63;

    float e = (tid < kP) ? es[b * kP + tid] : -1e30f;
    float wm = e;
    for (int off = 32; off; off >>= 1) wm = fmaxf(wm, __shfl_down(wm, off));
    if (lane == 0) red1[wave] = wm;
    __syncthreads();
    float gm = fmaxf(fmaxf(red1[0], red1[1]), fmaxf(red1[2], red1[3]));
    float ex = (tid < kP) ? expf(e - gm) : 0.f;
    float sw = ex;
    for (int off = 32; off; off >>= 1) sw += __shfl_down(sw, off);
    if (lane == 0) red2[wave] = sw;
    __syncthreads();
    float S = red2[0] + red2[1] + red2[2] + red2[3];
    float a = ex / S;
    if (tid < kP) al[tid] = a;
    else if (tid < kPT) al[tid] = 0.f;
    __syncthreads();

    if (x == 8) {
        if (tid < kP)
            alphas_out[((long long)b * kT + t) * kP + tid] = (t < declen[b]) ? a : 0.f;
        int tok = caps_i[b * kTCAP + t];
        for (int i = tid; i < 160; i += 256) {
            float4 v;
            if (i < 128) v = *(const float4*)(emb_table + (long long)tok * kEMB + i * 4);
            else         v = *(const float4*)(style + b * kLC + (i - 128) * 4);
            ushort4 o; o.x = f2b(v.x); o.y = f2b(v.y); o.z = f2b(v.z); o.w = f2b(v.w);
            *(ushort4*)(xh + (long long)b * kXH + i * 4) = o;
        }
        return;
    }

    int c = x * 256 + tid;                 // e2 col in [0,2048)
    float s = 0.f;
    if (mode == 2) {
        const ushort* r = encT + ((long long)b * kE + c) * kPT;
        #pragma unroll 5
        for (int i = 0; i < kPT / 8; i++) {
            uint4 u = *(const uint4*)(r + i * 8);
            const ushort* pu = (const ushort*)&u;
            f4 alo = *(const f4*)&al[i * 8];
            f4 ahi = *(const f4*)&al[i * 8 + 4];
            s += b2f(pu[0]) * alo.x + b2f(pu[1]) * alo.y + b2f(pu[2]) * alo.z + b2f(pu[3]) * alo.w;
            s += b2f(pu[4]) * ahi.x + b2f(pu[5]) * ahi.y + b2f(pu[6]) * ahi.z + b2f(pu[7]) * ahi.w;
        }
    } else if (mode == 1) {
        const ushort* base = encb + (long long)b * kP * kE + c;
        #pragma unroll 4
        for (int p = 0; p < kP; p++) s += b2f(base[(long long)p * kE]) * al[p];
    } else {
        const float* base = encf + (long long)sort_ind[b] * kP * kE + c;
        #pragma unroll 4
        for (int p = 0; p < kP; p++) s += base[(long long)p * kE] * al[p];
    }
    float g = gate[(long long)b * kE + c];
    float o = s / (1.f + expf(-g));
    xh[(long long)b * kXH + kEMB + kLC + c] = f2b(o);
}

// ---------------------------------------------------------------------------
// LSTM cell; reduces KZ split-K partials + gbias. h (bf16) -> xh[:,2688:3200]
// and Hbuf[t][b][:].
// ---------------------------------------------------------------------------
__global__ __launch_bounds__(256) void lstm_cell_kernel(
    const float* __restrict__ gpart, const float* __restrict__ gbias,
    ushort* __restrict__ xh, float* __restrict__ c,
    ushort* __restrict__ Hbuf, int t)
{
    int idx = blockIdx.x * 256 + threadIdx.x;   // b*512 + d
    int b = idx >> 9, d = idx & 511;
    float gi = gbias[d], gf = gbias[kD + d], gg = gbias[2 * kD + d], go = gbias[3 * kD + d];
    const float* g = gpart + (long long)b * 4 * kD + d;
    #pragma unroll
    for (int z = 0; z < KZ; z++) {
        const float* gz = g + (long long)z * kB * 4 * kD;
        gi += gz[0]; gf += gz[kD]; gg += gz[2 * kD]; go += gz[3 * kD];
    }
    float si = 1.f / (1.f + expf(-gi));
    float sf = 1.f / (1.f + expf(-gf));
    float so = 1.f / (1.f + expf(-go));
    float cn = sf * c[idx] + si * tanhf(gg);
    float hn = so * tanhf(cn);
    c[idx] = cn;
    ushort hb = f2b(hn);
    xh[(long long)b * kXH + kX + d] = hb;
    Hbuf[((long long)t * kB + b) * kD + d] = hb;
}

// ---------------------------------------------------------------------------
extern "C" void kernel_launch(void* const* d_in, const int* in_sizes, int n_in,
                              void* d_out, int out_size, void* d_ws, size_t ws_size,
                              hipStream_t stream)
{
    const float* encoder_out  = (const float*)d_in[0];
    const int*   enc_caps     = (const int*)  d_in[1];
    const int*   cap_lengths  = (const int*)  d_in[2];
    const int*   length_class = (const int*)  d_in[3];
    const float* W_enc_att = (const float*)d_in[4];
    const float* b_enc_att = (const float*)d_in[5];
    const float* W_dec_att = (const float*)d_in[6];
    const float* b_dec_att = (const float*)d_in[7];
    const float* w_full_att = (const float*)d_in[8];
    const float* b_full_att = (const float*)d_in[9];
    const float* W_init_h = (const float*)d_in[10];
    const float* b_init_h = (const float*)d_in[11];
    const float* W_init_c = (const float*)d_in[12];
    const float* b_init_c = (const float*)d_in[13];
    const float* W_fbeta  = (const float*)d_in[14];
    const float* b_fbeta  = (const float*)d_in[15];
    const float* emb_table = (const float*)d_in[16];
    const float* lc_table  = (const float*)d_in[17];
    const float* W_fc = (const float*)d_in[18];
    const float* b_fc = (const float*)d_in[19];
    const float* W_ih = (const float*)d_in[20];
    const float* b_ih = (const float*)d_in[21];
    const float* W_hh = (const float*)d_in[22];
    const float* b_hh = (const float*)d_in[23];

    // Output layout (flat float32, reference return order)
    float* out = (float*)d_out;
    float* o_pred    = out;                                  // B*T*V
    float* o_caps    = out + (long long)kB * kT * kV;
    float* o_declen  = o_caps + kB * kTCAP;
    float* o_alpha   = o_declen + kB;
    float* o_sortind = o_alpha + (long long)kB * kT * kP;

    // Workspace carve: f32 region, bf16 region, int region.
    float* w = (float*)d_ws;
    float* c        = w; w += kB * kD;
    float* att2     = w; w += kB * kA;
    float* gate     = w; w += kB * kE;
    float* mean_enc = w; w += kB * kE;
    float* gpart    = w; w += (long long)kB * 4 * kD * KZ;  // split-K partials
    float* es       = w; w += kB * kP;
    float* style    = w; w += kB * kLC;
    float* bias3    = w; w += kN3;
    float* bias_hc  = w; w += 1024;
    float* gbias    = w; w += 2048;
    ushort* us = (ushort*)w;
    ushort* xh_bf    = us; us += (long long)kB * kXH;       // bf16 [emb|style|awe|h]
    ushort* att1_bf  = us; us += (long long)kB * kP * kA;   // 12.85M
    ushort* WencT    = us; us += (long long)kA * kE;        // [512][2048]
    ushort* WhcT     = us; us += (long long)1024 * kE;      // [1024][2048]
    ushort* WcatT    = us; us += (long long)(4 * kD) * kXH; // [2048][3200]
    ushort* Wcat3T   = us; us += (long long)kN3 * kD;       // [12560][512]
    ushort* Hbuf     = us; us += (long long)kT * kB * kD;   // [25*128][512] bf16
    int* iw = (int*)us;
    int* sort_ind = iw; iw += kB;
    int* declen   = iw; iw += kB;
    int* caps_i   = iw; iw += kB * kTCAP;
    ushort* enc_bf = (ushort*)(iw + kB);                    // 102.8 MB (optional)
    ushort* enc_T  = enc_bf + (long long)kB * kP * kE;      // 104.9 MB (optional)

    // Decide enc paths by workspace headroom (ws_size is call-invariant).
    size_t need_encbf = ((char*)(enc_bf + (long long)kB * kP * kE)) - (char*)d_ws;
    size_t need_encT  = ((char*)(enc_T  + (long long)kB * kE * kPT)) - (char*)d_ws;
    int use_encbf = (ws_size >= need_encbf) ? 1 : 0;
    int use_encT  = (ws_size >= need_encT) ? 1 : 0;
    int mode = use_encT ? 2 : (use_encbf ? 1 : 0);

    sort_setup<<<1, 128, 0, stream>>>(cap_lengths, enc_caps, length_class, lc_table,
        sort_ind, declen, caps_i, style, o_caps, o_declen, o_sortind);

    // One-time weight prep: transpose-convert all B matrices to [N][K] bf16.
    auto tc = [&](const float* s, int ldsrc, int Kr, int Nc, ushort* d, long long ldd) {
        tcvt_kernel<<<dim3((Nc + 31) / 32, (Kr + 31) / 32), 256, 0, stream>>>(
            s, ldsrc, Kr, Nc, d, ldd);
    };
    tc(W_enc_att, kA, kE, kA, WencT, kE);                       // [512][2048]
    tc(W_init_h,  kD, kE, kD, WhcT, kE);                        // rows 0..512
    tc(W_init_c,  kD, kE, kD, WhcT + (long long)kD * kE, kE);   // rows 512..1024
    tc(W_ih, 4 * kD, kX, 4 * kD, WcatT, kXH);                   // k in [0,2688)
    tc(W_hh, 4 * kD, kD, 4 * kD, WcatT + kX, kXH);              // k in [2688,3200)
    tc(W_fc,      kV, kD, kV, Wcat3T, kD);                      // rows 0..10000
    tc(W_dec_att, kA, kD, kA, Wcat3T + (long long)kV * kD, kD); // rows 10000..10512
    tc(W_fbeta,   kE, kD, kE, Wcat3T + (long long)(kV + kA) * kD, kD);
    bias_setup_kernel<<<(kN3 + 1024 + 2048 + 255) / 256, 256, 0, stream>>>(
        b_fc, b_dec_att, b_fbeta, b_init_h, b_init_c, b_ih, b_hh, bias3, bias_hc, gbias);

    if (use_encbf) {
        enc_cvt_kernel<<<(unsigned)(((long long)kB * kP * kE / 4 + 255) / 256), 256, 0, stream>>>(
            encoder_out, sort_ind, enc_bf);
    }
    if (use_encT) {
        encT_kernel<<<dim3(kE / 64, kB), 256, 0, stream>>>(enc_bf, enc_T);
    }
    mean_enc_kernel<<<(kB * kE) / 256, 256, 0, stream>>>(
        encoder_out, enc_bf, enc_T, mode, sort_ind, mean_enc);

    auto g2 = [](int M, int N) { return dim3((unsigned)((N + 127) / 128), (unsigned)(M / 64)); };

    // h0 (bf16 -> xh_bf) | c0 (f32) in one GEMM (split epilogue)
    gemm2<<<g2(kB, 1024), 256, 0, stream>>>(mean_enc, kE, 0, WhcT, kE, bias_hc,
        xh_bf + kX, kXH, 1, 512, c, kD, kBIG, nullptr, 0, nullptr, 0, 0,
        kB, 1024, kE, 0);

    // att1 (bf16) = enc_sorted @ W_enc_att + b_enc_att
    if (use_encbf) {
        gemm_big<<<dim3(kA / 128, kB * kP / 128), 256, 0, stream>>>(
            enc_bf, kE, WencT, kE, b_enc_att,
            att1_bf, kA, 1, nullptr, 0, kB * kP, kA, kE);
    } else {
        gemm2<<<g2(kB * kP, kA), 256, 0, stream>>>(encoder_out, kE, 0, WencT, kE, b_enc_att,
            att1_bf, kA, 1, kBIG, nullptr, 0, kBIG, nullptr, 0, nullptr, 0, 0,
            kB * kP, kA, kE, 0);
    }

    // pre-loop: att2/gate for t=0 from h0 (A = bf16 h in xh_bf)
    gemm2<<<g2(kB, kA + kE), 256, 0, stream>>>(xh_bf + kX, kXH, 1,
        Wcat3T + (long long)kV * kD, kD, bias3 + kV, att2, kA, 0,
        kA, gate, kE, kBIG, nullptr, 0, nullptr, 0, 0, kB, kA + kE, kD, 0);

    const int* smap = use_encbf ? nullptr : sort_ind;
    for (int t = 0; t < kT; t++) {
        energy_kernel<<<dim3(2, kB), 512, 0, stream>>>(att1_bf, att2, w_full_att,
            b_full_att, es, smap);
        awe_kernel<<<dim3(9, kB), 256, 0, stream>>>(es, encoder_out, enc_bf, enc_T,
            mode, sort_ind, gate, caps_i, t, emb_table, style, xh_bf, o_alpha, declen);
        // gates partials via split-K (KZ slices of K=3200), A = bf16 xh
        gemm2<<<dim3((4 * kD + 127) / 128, kB / 64, KZ), 256, 0, stream>>>(
            xh_bf, kXH, 1, WcatT, kXH, nullptr,
            gpart, 4 * kD, 0, kBIG, nullptr, 0, kBIG, nullptr, 0, nullptr, 0, 0,
            kB, 4 * kD, kXH, (long long)kB * 4 * kD);
        lstm_cell_kernel<<<(kB * kD) / 256, 256, 0, stream>>>(gpart, gbias, xh_bf, c, Hbuf, t);
        // att2_{t+1} | gate_{t+1}  (A = bf16 h)
        gemm2<<<g2(kB, kA + kE), 256, 0, stream>>>(xh_bf + kX, kXH, 1,
            Wcat3T + (long long)kV * kD, kD, bias3 + kV, att2, kA, 0,
            kA, gate, kE, kBIG, nullptr, 0, nullptr, 0, 0, kB, kA + kE, kD, 0);
    }

    // Batched preds: [kT*kB, kV] = Hbuf @ W_fc + b_fc, masked by declen.
    gemm_big<<<dim3((kV + 127) / 128, kT * kB / 128), 256, 0, stream>>>(
        Hbuf, kD, Wcat3T, kD, bias3,
        o_pred, kV, 0, declen, 1, kT * kB, kV, kD);
}